// Round 8
// baseline (772.735 us; speedup 1.0000x reference)
//
#include <hip/hip_runtime.h>

#define N_ENT 14951
#define N_REL 1345
#define NNODE 120000
#define NEDGE 480000
#define MP_ENC 14976    // 234*64
#define KP_ENC 4608     // 8*576 >= 4396
#define NP_ENC 112
#define ENC_SPLIT 8
#define ENC_KSPLIT 576
#define ENC_STEPS 18    // 576/32
#define MROWS1 16320    // 255*64 >= N_ENT+N_REL
#define NB_E 118        // ceil(NNODE/1024)
#define NB_N 15         // ceil(N_ENT/1024)

static inline int ceil_div(int a, int b){ return (a + b - 1) / b; }

typedef __bf16 bf16x8 __attribute__((ext_vector_type(8)));
typedef float f32x4 __attribute__((ext_vector_type(4)));
union U8 { unsigned short u[8]; bf16x8 v; };

__device__ inline unsigned short f2bf(float f){
  unsigned u = __float_as_uint(f);
  return (unsigned short)((u + 0x7fffu + ((u >> 16) & 1u)) >> 16);
}
__device__ inline float bf2f(unsigned short b){
  return __uint_as_float(((unsigned)b) << 16);
}

// ---------------- encoder GEMM: LDS-free direct-fragment MFMA, split-K=8
// part[s][MP_ENC][112] += concat(img,txt)[:, s*576 .. +576] @ W^T
__global__ __launch_bounds__(256) void enc_mfma(
    const float* __restrict__ img, const float* __restrict__ txt,
    const unsigned short* __restrict__ Wt1, float* __restrict__ part)
{
  const int t = threadIdx.x;
  const int w = t >> 6, l = t & 63;
  const int s = blockIdx.y;
  const int row16 = blockIdx.x * 64 + w * 16;
  int row = row16 + (l & 15);
  if (row >= N_ENT) row = N_ENT - 1;     // clamp; rows >= N_ENT discarded in reduce
  const int koff = (l >> 4) * 8;
  f32x4 acc[7];
  #pragma unroll
  for (int i = 0; i < 7; i++) acc[i] = f32x4{0.f, 0.f, 0.f, 0.f};

  const float* irow = img + (size_t)row * 4096;
  const float* trow = txt + (size_t)row * 300;
  const unsigned short* bcol = Wt1 + (size_t)(l & 15) * KP_ENC;

  for (int step = 0; step < ENC_STEPS; ++step) {
    const int c = s * ENC_KSPLIT + step * 32 + koff;   // 8-aligned chunk start
    float4 u0 = make_float4(0.f, 0.f, 0.f, 0.f);
    float4 u1 = make_float4(0.f, 0.f, 0.f, 0.f);
    if (c + 8 <= 4096) {
      u0 = *(const float4*)(irow + c);
      u1 = *(const float4*)(irow + c + 4);
    } else if (c >= 4096) {
      const int ct_ = c - 4096;
      if (ct_ <= 288) {
        u0 = *(const float4*)(trow + ct_);
        u1 = *(const float4*)(trow + ct_ + 4);
      } else if (ct_ == 296) {
        u0 = *(const float4*)(trow + 296);   // last 4 txt floats
      }
    }
    U8 pa;
    pa.u[0] = f2bf(u0.x); pa.u[1] = f2bf(u0.y); pa.u[2] = f2bf(u0.z); pa.u[3] = f2bf(u0.w);
    pa.u[4] = f2bf(u1.x); pa.u[5] = f2bf(u1.y); pa.u[6] = f2bf(u1.z); pa.u[7] = f2bf(u1.w);
    const bf16x8 a = pa.v;
    #pragma unroll
    for (int ct = 0; ct < 7; ++ct) {
      const bf16x8 b = *(const bf16x8*)(bcol + (size_t)ct * 16 * KP_ENC + c);
      acc[ct] = __builtin_amdgcn_mfma_f32_16x16x32_bf16(a, b, acc[ct], 0, 0, 0);
    }
  }
  const int orow = row16 + (koff >> 1);   // (l>>4)*4
  float* pp = part + (size_t)s * MP_ENC * NP_ENC;
  #pragma unroll
  for (int ct = 0; ct < 7; ++ct)
    #pragma unroll
    for (int i = 0; i < 4; ++i)
      pp[(size_t)(orow + i) * NP_ENC + ct * 16 + (l & 15)] = acc[ct][i];
}

// reduce split-K partials + bias -> feat1 rows [0,N_ENT) cols [0,100), bf16
__global__ __launch_bounds__(256) void enc_reduce(
    const float* __restrict__ part, const float* __restrict__ bias,
    unsigned short* __restrict__ feat1)
{
  int i = blockIdx.x * 256 + threadIdx.x;
  if (i >= N_ENT * 100) return;
  int r = i / 100, c = i % 100;
  float v = bias[c];
  #pragma unroll
  for (int s = 0; s < ENC_SPLIT; ++s) v += part[((size_t)s * MP_ENC + r) * NP_ENC + c];
  feat1[(size_t)r * 224 + c] = f2bf(v);
}

// pack rin -> feat1 rows [N_ENT, N_ENT+N_REL) cols [100,200)
__global__ __launch_bounds__(256) void rin_pack(
    const float* __restrict__ rin, unsigned short* __restrict__ feat1)
{
  int i = blockIdx.x * 256 + threadIdx.x;
  if (i >= N_REL * 100) return;
  int r = i / 100, c = i % 100;
  feat1[(size_t)(N_ENT + r) * 224 + 100 + c] = f2bf(rin[i]);
}

// ---------------- generic LDS-free bf16 direct-fragment GEMM body
template<int NT, int KSTEPS, int LDA, int LDB>
__device__ inline void dgemm_body(
    const unsigned short* __restrict__ A, const unsigned short* __restrict__ Wt,
    int row16, int l, f32x4* acc)
{
  const int koff = (l >> 4) * 8;
  const unsigned short* arow = A + (size_t)(row16 + (l & 15)) * LDA + koff;
  const unsigned short* bcol = Wt + (size_t)(l & 15) * LDB + koff;
  for (int step = 0; step < KSTEPS; ++step) {
    const int k = step * 32;
    const bf16x8 a = *(const bf16x8*)(arow + k);
    #pragma unroll
    for (int ct = 0; ct < NT; ++ct) {
      const bf16x8 b = *(const bf16x8*)(bcol + (size_t)ct * 16 * LDB + k);
      acc[ct] = __builtin_amdgcn_mfma_f32_16x16x32_bf16(a, b, acc[ct], 0, 0, 0);
    }
  }
}

// egr1 = feat1[MROWS1,224] @ Wtg1^T -> bf16 [MROWS1,256]
__global__ __launch_bounds__(256) void egr1_mfma(
    const unsigned short* __restrict__ feat1, const unsigned short* __restrict__ Wtg1,
    unsigned short* __restrict__ egr1)
{
  const int t = threadIdx.x;
  const int w = t >> 6, l = t & 63;
  const int row16 = blockIdx.x * 64 + w * 16;
  f32x4 acc[16];
  #pragma unroll
  for (int i = 0; i < 16; i++) acc[i] = f32x4{0.f, 0.f, 0.f, 0.f};
  dgemm_body<16, 7, 224, 224>(feat1, Wtg1, row16, l, acc);
  const int orow = row16 + ((l >> 4) << 2);
  #pragma unroll
  for (int ct = 0; ct < 16; ++ct)
    #pragma unroll
    for (int i = 0; i < 4; ++i)
      egr1[(size_t)(orow + i) * 256 + ct * 16 + (l & 15)] = f2bf(acc[ct][i]);
}

// hg2 = h1[NNODE,256] @ Wt2^T -> bf16 [NNODE,208]
__global__ __launch_bounds__(256) void gemm2_mfma(
    const unsigned short* __restrict__ h1, const unsigned short* __restrict__ Wt2,
    unsigned short* __restrict__ hg2)
{
  const int t = threadIdx.x;
  const int w = t >> 6, l = t & 63;
  const int row16 = blockIdx.x * 64 + w * 16;
  f32x4 acc[13];
  #pragma unroll
  for (int i = 0; i < 13; i++) acc[i] = f32x4{0.f, 0.f, 0.f, 0.f};
  dgemm_body<13, 8, 256, 256>(h1, Wt2, row16, l, acc);
  const int orow = row16 + ((l >> 4) << 2);
  #pragma unroll
  for (int ct = 0; ct < 13; ++ct)
    #pragma unroll
    for (int i = 0; i < 4; ++i)
      hg2[(size_t)(orow + i) * 208 + ct * 16 + (l & 15)] = f2bf(acc[ct][i]);
}

// out_new = embA[14976,416] @ Wteo^T + b_eo -> f32, rows<N_ENT, cols<200
__global__ __launch_bounds__(256) void fin_mfma(
    const unsigned short* __restrict__ embA, const unsigned short* __restrict__ Wteo,
    const float* __restrict__ b_eo, float* __restrict__ out)
{
  const int t = threadIdx.x;
  const int w = t >> 6, l = t & 63;
  const int row16 = blockIdx.x * 64 + w * 16;
  f32x4 acc[13];
  #pragma unroll
  for (int i = 0; i < 13; i++) acc[i] = f32x4{0.f, 0.f, 0.f, 0.f};
  dgemm_body<13, 13, 416, 416>(embA, Wteo, row16, l, acc);
  const int orow = row16 + ((l >> 4) << 2);
  #pragma unroll
  for (int ct = 0; ct < 13; ++ct) {
    const int col = ct * 16 + (l & 15);
    if (col < 200) {
      const float b = b_eo[col];
      #pragma unroll
      for (int i = 0; i < 4; ++i) {
        const int r = orow + i;
        if (r < N_ENT) out[(size_t)r * 200 + col] = acc[ct][i] + b;
      }
    }
  }
}

// ---------------- fused weight prep: Wt1(enc), Wtg1, Wt2, Wteo
__global__ __launch_bounds__(256) void wt_all_k(
    const float* __restrict__ W_it, const float* __restrict__ W_g1,
    const float* __restrict__ W_g2, const float* __restrict__ W_eo,
    unsigned short* __restrict__ Wt1, unsigned short* __restrict__ Wtg1,
    unsigned short* __restrict__ Wt2, unsigned short* __restrict__ Wteo)
{
  int i = blockIdx.x * 256 + threadIdx.x;
  if (i < NP_ENC * KP_ENC) {
    int n = i / KP_ENC, k = i % KP_ENC;
    float v = (n < 100 && k < 4396) ? W_it[(size_t)k * 100 + n] : 0.f;
    Wt1[i] = f2bf(v);
    return;
  }
  i -= NP_ENC * KP_ENC;
  if (i < 256 * 224) {
    int n = i / 224, k = i % 224;
    float v = (k < 200) ? W_g1[(size_t)k * 256 + n] : 0.f;
    Wtg1[i] = f2bf(v);
    return;
  }
  i -= 256 * 224;
  if (i < 208 * 256) {
    int n = i >> 8, k = i & 255;
    float v = (n < 200) ? W_g2[(size_t)k * 200 + n] : 0.f;
    Wt2[i] = f2bf(v);
    return;
  }
  i -= 208 * 256;
  if (i < 208 * 416) {
    int n = i / 416, k = i % 416;
    float v = (n < 200 && k < 400) ? W_eo[(size_t)k * 200 + n] : 0.f;
    Wteo[i] = f2bf(v);
  }
}

// ---------------- generic f32 GEMM (small: relation encoders only)
template<bool RELU, bool HASBIAS>
__global__ __launch_bounds__(256) void gemm_f32(
    const float* __restrict__ A1, int K1, const float* __restrict__ A2,
    const float* __restrict__ B, const float* __restrict__ bias,
    float* __restrict__ C, int M, int K, int N)
{
  constexpr int BM = 64, BN = 128, BK = 16;
  __shared__ float As[BK][BM + 4];
  __shared__ float Bs[BK][BN];
  const int t = threadIdx.x;
  const int m0 = blockIdx.y * BM, n0 = blockIdx.x * BN;
  const int tr = t >> 4, tc = t & 15;
  const int tm0 = tr * 4, tn0 = tc * 8;
  const int K2 = K - K1;
  const int arow = t >> 2, aq = (t & 3) * 4;
  const int brow = t >> 4, bc0 = (t & 15) * 4;
  float acc[4][8];
  #pragma unroll
  for (int i = 0; i < 4; i++)
    #pragma unroll
    for (int j = 0; j < 8; j++) acc[i][j] = 0.f;

  for (int k0 = 0; k0 < K; k0 += BK) {
    {
      const int r = m0 + arow;
      const int k = k0 + aq;
      float4 v = make_float4(0.f, 0.f, 0.f, 0.f);
      if (r < M) {
        if (k + 3 < K1) {
          v = *(const float4*)(A1 + (size_t)r * K1 + k);
        } else if (k >= K1 && (k - K1) + 3 < K2) {
          v = *(const float4*)(A2 + (size_t)r * K2 + (k - K1));
        } else {
          float tmp[4] = {0.f, 0.f, 0.f, 0.f};
          #pragma unroll
          for (int j = 0; j < 4; j++) {
            int kj = k + j;
            if (kj < K) tmp[j] = (kj < K1) ? A1[(size_t)r * K1 + kj]
                                           : A2[(size_t)r * K2 + (kj - K1)];
          }
          v = make_float4(tmp[0], tmp[1], tmp[2], tmp[3]);
        }
      }
      As[aq + 0][arow] = v.x; As[aq + 1][arow] = v.y;
      As[aq + 2][arow] = v.z; As[aq + 3][arow] = v.w;
    }
    {
      const int k = k0 + brow;
      #pragma unroll
      for (int h = 0; h < 2; h++) {
        const int n = n0 + bc0 + h * 64;
        float4 v = make_float4(0.f, 0.f, 0.f, 0.f);
        if (k < K) {
          if (n + 3 < N) {
            v = *(const float4*)(B + (size_t)k * N + n);
          } else {
            float tmp[4] = {0.f, 0.f, 0.f, 0.f};
            for (int j = 0; j < 4; j++) if (n + j < N) tmp[j] = B[(size_t)k * N + n + j];
            v = make_float4(tmp[0], tmp[1], tmp[2], tmp[3]);
          }
        }
        *(float4*)&Bs[brow][bc0 + h * 64] = v;
      }
    }
    __syncthreads();
    #pragma unroll
    for (int k = 0; k < BK; k++) {
      float a[4], b[8];
      *(float4*)&a[0] = *(const float4*)&As[k][tm0];
      *(float4*)&b[0] = *(const float4*)&Bs[k][tn0];
      *(float4*)&b[4] = *(const float4*)&Bs[k][tn0 + 4];
      #pragma unroll
      for (int i = 0; i < 4; i++)
        #pragma unroll
        for (int j = 0; j < 8; j++) acc[i][j] = fmaf(a[i], b[j], acc[i][j]);
    }
    __syncthreads();
  }
  #pragma unroll
  for (int i = 0; i < 4; i++) {
    const int r = m0 + tm0 + i;
    if (r >= M) continue;
    #pragma unroll
    for (int j = 0; j < 8; j++) {
      const int c = n0 + tn0 + j;
      if (c >= N) continue;
      float v = acc[i][j];
      if (HASBIAS) v += bias[c];
      if (RELU) v = fmaxf(v, 0.f);
      C[(size_t)r * N + c] = v;
    }
  }
}

// ---------------- fused counting-sort infrastructure
__global__ __launch_bounds__(256) void hist2_k(
    const int* __restrict__ edst, const int* __restrict__ bx,
    int* __restrict__ ehist, int* __restrict__ nhist)
{
  int i = blockIdx.x * 256 + threadIdx.x;
  if (i < NEDGE) { atomicAdd(&ehist[edst[i]], 1); return; }
  i -= NEDGE;
  if (i < NNODE) atomicAdd(&nhist[bx[i]], 1);
}

__global__ __launch_bounds__(256) void scan1_k(
    const int* __restrict__ ehist, int* __restrict__ ebase, int* __restrict__ epart,
    const int* __restrict__ nhist, int* __restrict__ nbase, int* __restrict__ npart)
{
  __shared__ int s[256];
  const int t = threadIdx.x;
  const bool eregion = blockIdx.x < NB_E;
  const int b = eregion ? blockIdx.x : blockIdx.x - NB_E;
  const int n = eregion ? NNODE : N_ENT;
  const int* hist = eregion ? ehist : nhist;
  int* base = eregion ? ebase : nbase;
  int* partial = eregion ? epart : npart;
  const int i0 = b * 1024 + t * 4;
  int v[4];
  #pragma unroll
  for (int j = 0; j < 4; j++) v[j] = (i0 + j < n) ? hist[i0 + j] : 0;
  const int tsum = v[0] + v[1] + v[2] + v[3];
  s[t] = tsum;
  __syncthreads();
  #pragma unroll
  for (int off = 1; off < 256; off <<= 1) {
    int u = (t >= off) ? s[t - off] : 0;
    __syncthreads();
    s[t] += u;
    __syncthreads();
  }
  int run = s[t] - tsum;
  #pragma unroll
  for (int j = 0; j < 4; j++) {
    if (i0 + j < n) base[i0 + j] = run;
    run += v[j];
  }
  if (t == 255) partial[b] = s[255];
}

__global__ __launch_bounds__(256) void scan2_k(
    int* __restrict__ epart, int* __restrict__ ebase_end,
    int* __restrict__ npart, int* __restrict__ nbase_end)
{
  __shared__ int s[256];
  const int t = threadIdx.x;
  const bool eregion = blockIdx.x == 0;
  int* partial = eregion ? epart : npart;
  const int nb = eregion ? NB_E : NB_N;
  const int v = (t < nb) ? partial[t] : 0;
  s[t] = v;
  __syncthreads();
  #pragma unroll
  for (int off = 1; off < 256; off <<= 1) {
    int u = (t >= off) ? s[t - off] : 0;
    __syncthreads();
    s[t] += u;
    __syncthreads();
  }
  if (t < nb) partial[t] = s[t] - v;
  if (t == 255) *(eregion ? ebase_end : nbase_end) = s[255];
}

#define NB3_E 469  // ceil(NNODE/256)
__global__ __launch_bounds__(256) void scan3_k(
    int* __restrict__ ebase, const int* __restrict__ epart,
    int* __restrict__ nbase, const int* __restrict__ npart)
{
  if (blockIdx.x < NB3_E) {
    int i = blockIdx.x * 256 + threadIdx.x;
    if (i < NNODE) ebase[i] += epart[i >> 10];
  } else {
    int i = (blockIdx.x - NB3_E) * 256 + threadIdx.x;
    if (i < N_ENT) nbase[i] += npart[i >> 10];
  }
}

__global__ __launch_bounds__(256) void scatter2_k(
    const int* __restrict__ esrc, const int* __restrict__ edst, const float* __restrict__ ew,
    const int* __restrict__ bx, const int* __restrict__ bg,
    const int* __restrict__ ebase, int* __restrict__ ecur,
    float* __restrict__ s_w, int* __restrict__ s_src,
    int* __restrict__ s_en, int* __restrict__ s_gn,
    const int* __restrict__ nbase, int* __restrict__ ncur, int* __restrict__ node_of)
{
  int i = blockIdx.x * 256 + threadIdx.x;
  if (i < NEDGE) {
    int d = edst[i];
    int p = ebase[d] + atomicAdd(&ecur[d], 1);
    int s = esrc[i];
    s_w[p] = ew[i];
    s_src[p] = s;
    s_en[p] = bx[s];
    s_gn[p] = bg[s];
    return;
  }
  i -= NEDGE;
  if (i < NNODE) {
    int ent = bx[i];
    int p = nbase[ent] + atomicAdd(&ncur[ent], 1);
    node_of[p] = i;
  }
}

// ---------------- GCN layer 1 gather (bf16 table)
__global__ __launch_bounds__(256) void spmm1_g(
    const int* __restrict__ ebase, const float* __restrict__ s_w,
    const int* __restrict__ s_en, const int* __restrict__ s_gn,
    const unsigned short* __restrict__ egr1,
    const float* __restrict__ b_g1, unsigned short* __restrict__ h1)
{
  const int gid = blockIdx.x * blockDim.x + threadIdx.x;
  const int d = gid >> 6, lane = gid & 63;
  if (d >= NNODE) return;
  const int p0 = ebase[d], p1 = ebase[d + 1];
  float acc[4] = {0.f, 0.f, 0.f, 0.f};
  for (int p = p0; p < p1; ++p) {
    const float w = s_w[p];
    const int en = s_en[p], gn = s_gn[p];
    const ushort4 va = *(const ushort4*)(egr1 + (size_t)en * 256 + lane * 4);
    const ushort4 vb = *(const ushort4*)(egr1 + (size_t)(N_ENT + gn) * 256 + lane * 4);
    acc[0] += w * (bf2f(va.x) + bf2f(vb.x));
    acc[1] += w * (bf2f(va.y) + bf2f(vb.y));
    acc[2] += w * (bf2f(va.z) + bf2f(vb.z));
    acc[3] += w * (bf2f(va.w) + bf2f(vb.w));
  }
  const float4 b = ((const float4*)b_g1)[lane];
  ushort4 o;
  o.x = f2bf(fmaxf(acc[0] + b.x, 0.f));
  o.y = f2bf(fmaxf(acc[1] + b.y, 0.f));
  o.z = f2bf(fmaxf(acc[2] + b.z, 0.f));
  o.w = f2bf(fmaxf(acc[3] + b.w, 0.f));
  *(ushort4*)(h1 + (size_t)d * 256 + lane * 4) = o;
}

// ---------------- GCN layer 2 gather + bias + fused score; h2 bf16
__global__ __launch_bounds__(256) void spmm2_g(
    const int* __restrict__ ebase, const float* __restrict__ s_w,
    const int* __restrict__ s_src, const unsigned short* __restrict__ hg2,
    const float* __restrict__ b_g2, const float* __restrict__ W_e,
    unsigned short* __restrict__ h2, float* __restrict__ score)
{
  const int gid = blockIdx.x * blockDim.x + threadIdx.x;
  const int d = gid >> 6, lane = gid & 63;
  if (d >= NNODE) return;
  const int p0 = ebase[d], p1 = ebase[d + 1];
  float acc[4] = {0.f, 0.f, 0.f, 0.f};
  const int col = lane * 4;
  float sp = 0.f;
  if (lane < 50) {
    for (int p = p0; p < p1; ++p) {
      const float w = s_w[p];
      const ushort4 v = *(const ushort4*)(hg2 + (size_t)s_src[p] * 208 + col);
      acc[0] += w * bf2f(v.x); acc[1] += w * bf2f(v.y);
      acc[2] += w * bf2f(v.z); acc[3] += w * bf2f(v.w);
    }
    const float4 b = ((const float4*)b_g2)[lane];
    acc[0] += b.x; acc[1] += b.y; acc[2] += b.z; acc[3] += b.w;
    ushort4 o;
    o.x = f2bf(acc[0]); o.y = f2bf(acc[1]); o.z = f2bf(acc[2]); o.w = f2bf(acc[3]);
    *(ushort4*)(h2 + (size_t)d * 200 + col) = o;
    const float4 we = ((const float4*)W_e)[lane];
    sp = acc[0] * we.x + acc[1] * we.y + acc[2] * we.z + acc[3] * we.w;
  }
  #pragma unroll
  for (int off = 32; off; off >>= 1) sp += __shfl_xor(sp, off);
  if (lane == 0) score[d] = sp;
}

// ---------------- per-entity softmax + weighted sum + mean -> embA bf16 [14976][416]
__global__ __launch_bounds__(256) void ent_k(
    const int* __restrict__ nbase, const int* __restrict__ node_of,
    const unsigned short* __restrict__ h2, const float* __restrict__ score,
    unsigned short* __restrict__ embA)
{
  const int gid = blockIdx.x * blockDim.x + threadIdx.x;
  const int ent = gid >> 6, lane = gid & 63;
  if (ent >= N_ENT) return;
  const int p0 = nbase[ent], p1 = nbase[ent + 1];
  const int cnt = p1 - p0;
  float m = -3.4e38f;
  for (int p = p0 + lane; p < p1; p += 64) m = fmaxf(m, score[node_of[p]]);
  #pragma unroll
  for (int off = 32; off; off >>= 1) m = fmaxf(m, __shfl_xor(m, off));
  float es = 0.f;
  for (int p = p0 + lane; p < p1; p += 64) es += __expf(score[node_of[p]] - m);
  #pragma unroll
  for (int off = 32; off; off >>= 1) es += __shfl_xor(es, off);
  const float inv_es = (cnt > 0) ? 1.f / es : 0.f;
  const float inv_cnt = 1.f / fmaxf((float)cnt, 1.f);
  float aw[4] = {0.f, 0.f, 0.f, 0.f};
  float am[4] = {0.f, 0.f, 0.f, 0.f};
  for (int p = p0; p < p1; ++p) {
    const int nd = node_of[p];
    const float z = __expf(score[nd] - m) * inv_es;
    if (lane < 50) {
      const ushort4 v = *(const ushort4*)(h2 + (size_t)nd * 200 + lane * 4);
      const float vx = bf2f(v.x), vy = bf2f(v.y), vz = bf2f(v.z), vw = bf2f(v.w);
      aw[0] += z * vx; aw[1] += z * vy; aw[2] += z * vz; aw[3] += z * vw;
      am[0] += vx; am[1] += vy; am[2] += vz; am[3] += vw;
    }
  }
  if (lane < 50) {
    ushort4 ow, om;
    ow.x = f2bf(aw[0]); ow.y = f2bf(aw[1]); ow.z = f2bf(aw[2]); ow.w = f2bf(aw[3]);
    om.x = f2bf(am[0] * inv_cnt); om.y = f2bf(am[1] * inv_cnt);
    om.z = f2bf(am[2] * inv_cnt); om.w = f2bf(am[3] * inv_cnt);
    *(ushort4*)(embA + (size_t)ent * 416 + lane * 4) = ow;
    *(ushort4*)(embA + (size_t)ent * 416 + 200 + lane * 4) = om;
  }
}

extern "C" void kernel_launch(void* const* d_in, const int* in_sizes, int n_in,
                              void* d_out, int out_size, void* d_ws, size_t ws_size,
                              hipStream_t stream)
{
  const float* img  = (const float*)d_in[0];
  const float* txt  = (const float*)d_in[1];
  const float* rel  = (const float*)d_in[2];
  const float* W_it = (const float*)d_in[3];
  const float* b_it = (const float*)d_in[4];
  const float* W_ri = (const float*)d_in[5];
  const float* b_ri = (const float*)d_in[6];
  const float* W_g1 = (const float*)d_in[7];
  const float* b_g1 = (const float*)d_in[8];
  const float* W_g2 = (const float*)d_in[9];
  const float* b_g2 = (const float*)d_in[10];
  const float* W_e  = (const float*)d_in[11];
  const float* W_eo = (const float*)d_in[13];
  const float* b_eo = (const float*)d_in[14];
  const float* W_r  = (const float*)d_in[15];
  const float* b_r  = (const float*)d_in[16];
  const float* ew   = (const float*)d_in[17];
  const int*   bx   = (const int*)d_in[18];
  const int*   bg   = (const int*)d_in[19];
  const int*   esrc = (const int*)d_in[20];
  const int*   edst = (const int*)d_in[21];

  float* ws = (float*)d_ws;
  size_t off = 0;
  auto alloc = [&](size_t n){ size_t r = off; off += (n + 255) & ~(size_t)255; return r; };
  unsigned short* feat1 = (unsigned short*)(ws + alloc((size_t)MROWS1 * 224 / 2));
  unsigned short* egr1  = (unsigned short*)(ws + alloc((size_t)MROWS1 * 256 / 2));
  unsigned short* h1    = (unsigned short*)(ws + alloc((size_t)NNODE * 256 / 2));
  unsigned short* hg2   = (unsigned short*)(ws + alloc((size_t)NNODE * 208 / 2));
  unsigned short* embA  = (unsigned short*)(ws + alloc((size_t)MP_ENC * 416 / 2));
  unsigned short* h2    = (unsigned short*)(ws + alloc((size_t)NNODE * 200 / 2));
  float* part  = ws + alloc((size_t)ENC_SPLIT * MP_ENC * NP_ENC);
  float* rin   = ws + alloc((size_t)N_REL * 100);
  float* score = ws + alloc(NNODE);
  size_t cnt0 = alloc((size_t)NNODE * 2 + (size_t)N_ENT * 2);
  int* ehist = (int*)(ws + cnt0);
  int* ecur  = ehist + NNODE;
  int* nhist = ecur + NNODE;
  int* ncur  = nhist + N_ENT;
  int* ebase = (int*)(ws + alloc(NNODE + 1));
  int* nbase = (int*)(ws + alloc(N_ENT + 1));
  int* epart = (int*)(ws + alloc(256));
  int* npart = (int*)(ws + alloc(256));
  float* s_w  = ws + alloc(NEDGE);
  int* s_src  = (int*)(ws + alloc(NEDGE));
  int* s_en   = (int*)(ws + alloc(NEDGE));
  int* s_gn   = (int*)(ws + alloc(NEDGE));
  int* node_of = (int*)(ws + alloc(NNODE));
  unsigned short* Wt1  = (unsigned short*)(ws + alloc((size_t)NP_ENC * KP_ENC / 2));
  unsigned short* Wtg1 = (unsigned short*)(ws + alloc((size_t)256 * 224 / 2));
  unsigned short* Wt2  = (unsigned short*)(ws + alloc((size_t)208 * 256 / 2));
  unsigned short* Wteo = (unsigned short*)(ws + alloc((size_t)208 * 416 / 2));

  dim3 blk(256);

  // ---- memsets
  hipMemsetAsync(ehist, 0, ((size_t)NNODE * 2 + (size_t)N_ENT * 2) * 4, stream);
  hipMemsetAsync(feat1, 0, (size_t)MROWS1 * 224 * 2, stream);
  hipMemsetAsync(embA,  0, (size_t)MP_ENC * 416 * 2, stream);

  // ---- CSR build
  hist2_k<<<ceil_div(NEDGE + NNODE, 256), blk, 0, stream>>>(edst, bx, ehist, nhist);
  scan1_k<<<NB_E + NB_N, blk, 0, stream>>>(ehist, ebase, epart, nhist, nbase, npart);
  scan2_k<<<2, blk, 0, stream>>>(epart, ebase + NNODE, npart, nbase + N_ENT);
  scan3_k<<<NB3_E + ceil_div(N_ENT, 256), blk, 0, stream>>>(ebase, epart, nbase, npart);
  scatter2_k<<<ceil_div(NEDGE + NNODE, 256), blk, 0, stream>>>(
      esrc, edst, ew, bx, bg, ebase, ecur, s_w, s_src, s_en, s_gn, nbase, ncur, node_of);

  // ---- weight prep (fused)
  wt_all_k<<<ceil_div(NP_ENC * KP_ENC + 256 * 224 + 208 * 256 + 208 * 416, 256), blk, 0, stream>>>(
      W_it, W_g1, W_g2, W_eo, Wt1, Wtg1, Wt2, Wteo);

  // ---- encoders
  enc_mfma<<<dim3(MP_ENC / 64, ENC_SPLIT), blk, 0, stream>>>(img, txt, Wt1, part);
  enc_reduce<<<ceil_div(N_ENT * 100, 256), blk, 0, stream>>>(part, b_it, feat1);
  gemm_f32<true, true><<<dim3(1, ceil_div(N_REL, 64)), blk, 0, stream>>>(
      rel, 300, rel, W_ri, b_ri, rin, N_REL, 300, 100);
  rin_pack<<<ceil_div(N_REL * 100, 256), blk, 0, stream>>>(rin, feat1);

  // ---- combined table + GCN layer 1 gather
  egr1_mfma<<<MROWS1 / 64, blk, 0, stream>>>(feat1, Wtg1, egr1);
  spmm1_g<<<ceil_div(NNODE * 64, 256), blk, 0, stream>>>(
      ebase, s_w, s_en, s_gn, egr1, b_g1, h1);

  // ---- GCN layer 2
  gemm2_mfma<<<NNODE / 64, blk, 0, stream>>>(h1, Wt2, hg2);
  spmm2_g<<<ceil_div(NNODE * 64, 256), blk, 0, stream>>>(
      ebase, s_w, s_src, hg2, b_g2, W_e, h2, score);

  // ---- per-entity softmax + weighted sum + mean -> embA (bf16)
  ent_k<<<ceil_div(N_ENT * 64, 256), blk, 0, stream>>>(nbase, node_of, h2, score, embA);

  // ---- final projections
  float* out_new = (float*)d_out;
  float* out_rel = out_new + (size_t)N_ENT * 200;
  fin_mfma<<<MP_ENC / 64, blk, 0, stream>>>(embA, Wteo, b_eo, out_new);
  gemm_f32<true, true><<<dim3(2, ceil_div(N_REL, 64)), blk, 0, stream>>>(
      rel, 300, rel, W_r, b_r, out_rel, N_REL, 300, 200);
}

// Round 9
// 677.887 us; speedup vs baseline: 1.1399x; 1.1399x over previous
//
#include <hip/hip_runtime.h>

#define N_ENT 14951
#define N_REL 1345
#define NNODE 120000
#define NEDGE 480000
#define MP_ENC 14976    // 234*64
#define KP_ENC 4608     // 8*576 >= 4396
#define NP_ENC 112
#define ENC_SPLIT 8
#define ENC_KSPLIT 576
#define ENC_STEPS 18    // 576/32
#define ENC_LDSTRIDE 584
#define MROWS1 16320    // 255*64 >= N_ENT+N_REL
#define NB_E 118        // ceil(NNODE/1024)
#define NB_N 15         // ceil(N_ENT/1024)

static inline int ceil_div(int a, int b){ return (a + b - 1) / b; }

typedef __bf16 bf16x8 __attribute__((ext_vector_type(8)));
typedef float f32x4 __attribute__((ext_vector_type(4)));
union U8 { unsigned short u[8]; bf16x8 v; };

__device__ inline unsigned short f2bf(float f){
  unsigned u = __float_as_uint(f);
  return (unsigned short)((u + 0x7fffu + ((u >> 16) & 1u)) >> 16);
}
__device__ inline float bf2f(unsigned short b){
  return __uint_as_float(((unsigned)b) << 16);
}

// ---------------- encoder GEMM: B-slice in LDS once, A streamed with 2-deep
// register prefetch, NO per-step barriers. split-K=8.
__global__ __launch_bounds__(256) void enc_mfma(
    const float* __restrict__ img, const float* __restrict__ txt,
    const unsigned short* __restrict__ Wt1, float* __restrict__ part)
{
  __shared__ unsigned short Bs[112 * ENC_LDSTRIDE];   // 130,816 B
  const int t = threadIdx.x;
  const int w = t >> 6, l = t & 63;
  const int s = blockIdx.y;
  const int row16 = blockIdx.x * 64 + w * 16;
  int row = row16 + (l & 15);
  if (row >= N_ENT) row = N_ENT - 1;     // clamp; surplus rows ignored by reduce
  const int koff = (l >> 4) * 8;

  // ---- stage the 112 x 576 bf16 weight slice once (contiguous 16B chunks)
  for (int idx = t; idx < 112 * 72; idx += 256) {
    const int col = idx / 72, kc = idx - col * 72;
    *(uint4*)&Bs[col * ENC_LDSTRIDE + kc * 8] =
        *(const uint4*)(Wt1 + (size_t)col * KP_ENC + s * ENC_KSPLIT + kc * 8);
  }
  __syncthreads();   // the only barrier

  f32x4 acc[7];
  #pragma unroll
  for (int i = 0; i < 7; i++) acc[i] = f32x4{0.f, 0.f, 0.f, 0.f};

  const float* irow = img + (size_t)row * 4096;
  const float* trow = txt + (size_t)row * 300;
  const int kbase = s * ENC_KSPLIT + koff;

  auto loadA = [&](int step, float4& u0, float4& u1) {
    u0 = make_float4(0.f, 0.f, 0.f, 0.f);
    u1 = make_float4(0.f, 0.f, 0.f, 0.f);
    if (step < ENC_STEPS) {
      const int c = kbase + step * 32;
      if (c + 8 <= 4096) {
        u0 = *(const float4*)(irow + c);
        u1 = *(const float4*)(irow + c + 4);
      } else if (c >= 4096) {
        const int ct_ = c - 4096;
        if (ct_ <= 288) {
          u0 = *(const float4*)(trow + ct_);
          u1 = *(const float4*)(trow + ct_ + 4);
        } else if (ct_ == 296) {
          u0 = *(const float4*)(trow + 296);
        }
      }
    }
  };
  auto compute = [&](int step, const float4& u0, const float4& u1) {
    U8 pa;
    pa.u[0] = f2bf(u0.x); pa.u[1] = f2bf(u0.y); pa.u[2] = f2bf(u0.z); pa.u[3] = f2bf(u0.w);
    pa.u[4] = f2bf(u1.x); pa.u[5] = f2bf(u1.y); pa.u[6] = f2bf(u1.z); pa.u[7] = f2bf(u1.w);
    const bf16x8 a = pa.v;
    const int kl = step * 32 + koff;
    #pragma unroll
    for (int ct = 0; ct < 7; ++ct) {
      const bf16x8 b = *(const bf16x8*)&Bs[(ct * 16 + (l & 15)) * ENC_LDSTRIDE + kl];
      acc[ct] = __builtin_amdgcn_mfma_f32_16x16x32_bf16(a, b, acc[ct], 0, 0, 0);
    }
  };

  float4 a0, a1, b0, b1;
  loadA(0, a0, a1);
  for (int step = 0; step < ENC_STEPS; step += 2) {
    loadA(step + 1, b0, b1);
    compute(step, a0, a1);
    loadA(step + 2, a0, a1);
    compute(step + 1, b0, b1);
  }

  const int orow = row16 + (koff >> 1);   // (l>>4)*4
  float* pp = part + (size_t)s * MP_ENC * NP_ENC;
  #pragma unroll
  for (int ct = 0; ct < 7; ++ct)
    #pragma unroll
    for (int i = 0; i < 4; ++i)
      pp[(size_t)(orow + i) * NP_ENC + ct * 16 + (l & 15)] = acc[ct][i];
}

// reduce split-K partials + bias -> feat1 rows [0,N_ENT) cols [0,100), bf16
__global__ __launch_bounds__(256) void enc_reduce(
    const float* __restrict__ part, const float* __restrict__ bias,
    unsigned short* __restrict__ feat1)
{
  int i = blockIdx.x * 256 + threadIdx.x;
  if (i >= N_ENT * 100) return;
  int r = i / 100, c = i % 100;
  float v = bias[c];
  #pragma unroll
  for (int s = 0; s < ENC_SPLIT; ++s) v += part[((size_t)s * MP_ENC + r) * NP_ENC + c];
  feat1[(size_t)r * 224 + c] = f2bf(v);
}

// pack rin -> feat1 rows [N_ENT, N_ENT+N_REL) cols [100,200)
__global__ __launch_bounds__(256) void rin_pack(
    const float* __restrict__ rin, unsigned short* __restrict__ feat1)
{
  int i = blockIdx.x * 256 + threadIdx.x;
  if (i >= N_REL * 100) return;
  int r = i / 100, c = i % 100;
  feat1[(size_t)(N_ENT + r) * 224 + 100 + c] = f2bf(rin[i]);
}

// ---------------- egr1 = feat1[MROWS1,224] @ Wtg1^T -> bf16 [MROWS1,256] (R6 staged)
__global__ __launch_bounds__(256) void egr1_mfma(
    const unsigned short* __restrict__ feat1, const unsigned short* __restrict__ Wtg1,
    unsigned short* __restrict__ egr1)
{
  __shared__ unsigned short As[64 * 40];
  __shared__ unsigned short Bs[256 * 40];
  const int t = threadIdx.x;
  const int m0 = blockIdx.x * 64;
  const int l = t & 63, w = t >> 6;
  f32x4 acc[16];
  #pragma unroll
  for (int i = 0; i < 16; i++) acc[i] = f32x4{0.f, 0.f, 0.f, 0.f};

  for (int step = 0; step < 7; ++step) {
    const int kb = step * 32;
    {
      const int row = t >> 2, kc = t & 3;
      *(uint4*)&As[row * 40 + kc * 8] = *(const uint4*)(feat1 + (size_t)(m0 + row) * 224 + kb + kc * 8);
    }
    #pragma unroll
    for (int p = 0; p < 4; ++p) {
      const int c = t + p * 256;
      const int n = c >> 2, k16 = c & 3;
      *(uint4*)&Bs[n * 40 + k16 * 8] = *(const uint4*)(Wtg1 + (size_t)n * 224 + kb + k16 * 8);
    }
    __syncthreads();
    bf16x8 a = *(const bf16x8*)&As[(w * 16 + (l & 15)) * 40 + (l >> 4) * 8];
    #pragma unroll
    for (int ct = 0; ct < 16; ++ct) {
      bf16x8 bb = *(const bf16x8*)&Bs[(ct * 16 + (l & 15)) * 40 + (l >> 4) * 8];
      acc[ct] = __builtin_amdgcn_mfma_f32_16x16x32_bf16(a, bb, acc[ct], 0, 0, 0);
    }
    __syncthreads();
  }
  const int rb = m0 + w * 16 + (l >> 4) * 4;
  const int col0 = l & 15;
  #pragma unroll
  for (int ct = 0; ct < 16; ++ct) {
    const int col = ct * 16 + col0;
    #pragma unroll
    for (int i = 0; i < 4; ++i)
      egr1[(size_t)(rb + i) * 256 + col] = f2bf(acc[ct][i]);
  }
}

// ---------------- hg2 = h1[NNODE,256](bf16) @ Wt2^T -> bf16 [NNODE,208] (R6 staged)
__global__ __launch_bounds__(256) void gemm2_mfma(
    const unsigned short* __restrict__ h1, const unsigned short* __restrict__ Wt2,
    unsigned short* __restrict__ hg2)
{
  __shared__ unsigned short As[64 * 40];
  __shared__ unsigned short Bs[208 * 40];
  const int t = threadIdx.x;
  const int m0 = blockIdx.x * 64;
  const int l = t & 63, w = t >> 6;
  f32x4 acc[13];
  #pragma unroll
  for (int i = 0; i < 13; i++) acc[i] = f32x4{0.f, 0.f, 0.f, 0.f};

  for (int step = 0; step < 8; ++step) {
    const int kb = step * 32;
    {
      const int row = t >> 2, kc = t & 3;
      *(uint4*)&As[row * 40 + kc * 8] = *(const uint4*)(h1 + (size_t)(m0 + row) * 256 + kb + kc * 8);
    }
    #pragma unroll
    for (int p = 0; p < 4; ++p) {
      const int c = t + p * 256;
      if (c < 832) {
        const int n = c >> 2, k16 = c & 3;
        *(uint4*)&Bs[n * 40 + k16 * 8] = *(const uint4*)(Wt2 + (size_t)n * 256 + kb + k16 * 8);
      }
    }
    __syncthreads();
    bf16x8 a = *(const bf16x8*)&As[(w * 16 + (l & 15)) * 40 + (l >> 4) * 8];
    #pragma unroll
    for (int ct = 0; ct < 13; ++ct) {
      bf16x8 bb = *(const bf16x8*)&Bs[(ct * 16 + (l & 15)) * 40 + (l >> 4) * 8];
      acc[ct] = __builtin_amdgcn_mfma_f32_16x16x32_bf16(a, bb, acc[ct], 0, 0, 0);
    }
    __syncthreads();
  }
  const int rb = m0 + w * 16 + (l >> 4) * 4;
  const int col0 = l & 15;
  #pragma unroll
  for (int ct = 0; ct < 13; ++ct) {
    const int col = ct * 16 + col0;
    #pragma unroll
    for (int i = 0; i < 4; ++i)
      hg2[(size_t)(rb + i) * 208 + col] = f2bf(acc[ct][i]);
  }
}

// ---------------- out_new = embA[14976,416](bf16) @ Wteo^T + b_eo (R6 staged)
__global__ __launch_bounds__(256) void fin_mfma(
    const unsigned short* __restrict__ embA, const unsigned short* __restrict__ Wteo,
    const float* __restrict__ b_eo, float* __restrict__ out)
{
  __shared__ unsigned short As[64 * 40];
  __shared__ unsigned short Bs[208 * 40];
  const int t = threadIdx.x;
  const int m0 = blockIdx.x * 64;
  const int l = t & 63, w = t >> 6;
  f32x4 acc[13];
  #pragma unroll
  for (int i = 0; i < 13; i++) acc[i] = f32x4{0.f, 0.f, 0.f, 0.f};

  for (int step = 0; step < 13; ++step) {
    const int kb = step * 32;
    {
      const int row = t >> 2, kc = t & 3;
      *(uint4*)&As[row * 40 + kc * 8] = *(const uint4*)(embA + (size_t)(m0 + row) * 416 + kb + kc * 8);
    }
    #pragma unroll
    for (int p = 0; p < 4; ++p) {
      const int c = t + p * 256;
      if (c < 832) {
        const int n = c >> 2, k16 = c & 3;
        *(uint4*)&Bs[n * 40 + k16 * 8] = *(const uint4*)(Wteo + (size_t)n * 416 + kb + k16 * 8);
      }
    }
    __syncthreads();
    bf16x8 a = *(const bf16x8*)&As[(w * 16 + (l & 15)) * 40 + (l >> 4) * 8];
    #pragma unroll
    for (int ct = 0; ct < 13; ++ct) {
      bf16x8 bb = *(const bf16x8*)&Bs[(ct * 16 + (l & 15)) * 40 + (l >> 4) * 8];
      acc[ct] = __builtin_amdgcn_mfma_f32_16x16x32_bf16(a, bb, acc[ct], 0, 0, 0);
    }
    __syncthreads();
  }
  const int rb = m0 + w * 16 + (l >> 4) * 4;
  const int col0 = l & 15;
  #pragma unroll
  for (int ct = 0; ct < 13; ++ct) {
    const int col = ct * 16 + col0;
    if (col < 200) {
      const float b = b_eo[col];
      #pragma unroll
      for (int i = 0; i < 4; ++i) {
        const int r = rb + i;
        if (r < N_ENT) out[(size_t)r * 200 + col] = acc[ct][i] + b;
      }
    }
  }
}

// ---------------- fused weight prep: Wt1(enc), Wtg1, Wt2, Wteo
__global__ __launch_bounds__(256) void wt_all_k(
    const float* __restrict__ W_it, const float* __restrict__ W_g1,
    const float* __restrict__ W_g2, const float* __restrict__ W_eo,
    unsigned short* __restrict__ Wt1, unsigned short* __restrict__ Wtg1,
    unsigned short* __restrict__ Wt2, unsigned short* __restrict__ Wteo)
{
  int i = blockIdx.x * 256 + threadIdx.x;
  if (i < NP_ENC * KP_ENC) {
    int n = i / KP_ENC, k = i % KP_ENC;
    float v = (n < 100 && k < 4396) ? W_it[(size_t)k * 100 + n] : 0.f;
    Wt1[i] = f2bf(v);
    return;
  }
  i -= NP_ENC * KP_ENC;
  if (i < 256 * 224) {
    int n = i / 224, k = i % 224;
    float v = (k < 200) ? W_g1[(size_t)k * 256 + n] : 0.f;
    Wtg1[i] = f2bf(v);
    return;
  }
  i -= 256 * 224;
  if (i < 208 * 256) {
    int n = i >> 8, k = i & 255;
    float v = (n < 200) ? W_g2[(size_t)k * 200 + n] : 0.f;
    Wt2[i] = f2bf(v);
    return;
  }
  i -= 208 * 256;
  if (i < 208 * 416) {
    int n = i / 416, k = i % 416;
    float v = (n < 200 && k < 400) ? W_eo[(size_t)k * 200 + n] : 0.f;
    Wteo[i] = f2bf(v);
  }
}

// ---------------- generic f32 GEMM (small: relation encoders only)
template<bool RELU, bool HASBIAS>
__global__ __launch_bounds__(256) void gemm_f32(
    const float* __restrict__ A1, int K1, const float* __restrict__ A2,
    const float* __restrict__ B, const float* __restrict__ bias,
    float* __restrict__ C, int M, int K, int N)
{
  constexpr int BM = 64, BN = 128, BK = 16;
  __shared__ float As[BK][BM + 4];
  __shared__ float Bs[BK][BN];
  const int t = threadIdx.x;
  const int m0 = blockIdx.y * BM, n0 = blockIdx.x * BN;
  const int tr = t >> 4, tc = t & 15;
  const int tm0 = tr * 4, tn0 = tc * 8;
  const int K2 = K - K1;
  const int arow = t >> 2, aq = (t & 3) * 4;
  const int brow = t >> 4, bc0 = (t & 15) * 4;
  float acc[4][8];
  #pragma unroll
  for (int i = 0; i < 4; i++)
    #pragma unroll
    for (int j = 0; j < 8; j++) acc[i][j] = 0.f;

  for (int k0 = 0; k0 < K; k0 += BK) {
    {
      const int r = m0 + arow;
      const int k = k0 + aq;
      float4 v = make_float4(0.f, 0.f, 0.f, 0.f);
      if (r < M) {
        if (k + 3 < K1) {
          v = *(const float4*)(A1 + (size_t)r * K1 + k);
        } else if (k >= K1 && (k - K1) + 3 < K2) {
          v = *(const float4*)(A2 + (size_t)r * K2 + (k - K1));
        } else {
          float tmp[4] = {0.f, 0.f, 0.f, 0.f};
          #pragma unroll
          for (int j = 0; j < 4; j++) {
            int kj = k + j;
            if (kj < K) tmp[j] = (kj < K1) ? A1[(size_t)r * K1 + kj]
                                           : A2[(size_t)r * K2 + (kj - K1)];
          }
          v = make_float4(tmp[0], tmp[1], tmp[2], tmp[3]);
        }
      }
      As[aq + 0][arow] = v.x; As[aq + 1][arow] = v.y;
      As[aq + 2][arow] = v.z; As[aq + 3][arow] = v.w;
    }
    {
      const int k = k0 + brow;
      #pragma unroll
      for (int h = 0; h < 2; h++) {
        const int n = n0 + bc0 + h * 64;
        float4 v = make_float4(0.f, 0.f, 0.f, 0.f);
        if (k < K) {
          if (n + 3 < N) {
            v = *(const float4*)(B + (size_t)k * N + n);
          } else {
            float tmp[4] = {0.f, 0.f, 0.f, 0.f};
            for (int j = 0; j < 4; j++) if (n + j < N) tmp[j] = B[(size_t)k * N + n + j];
            v = make_float4(tmp[0], tmp[1], tmp[2], tmp[3]);
          }
        }
        *(float4*)&Bs[brow][bc0 + h * 64] = v;
      }
    }
    __syncthreads();
    #pragma unroll
    for (int k = 0; k < BK; k++) {
      float a[4], b[8];
      *(float4*)&a[0] = *(const float4*)&As[k][tm0];
      *(float4*)&b[0] = *(const float4*)&Bs[k][tn0];
      *(float4*)&b[4] = *(const float4*)&Bs[k][tn0 + 4];
      #pragma unroll
      for (int i = 0; i < 4; i++)
        #pragma unroll
        for (int j = 0; j < 8; j++) acc[i][j] = fmaf(a[i], b[j], acc[i][j]);
    }
    __syncthreads();
  }
  #pragma unroll
  for (int i = 0; i < 4; i++) {
    const int r = m0 + tm0 + i;
    if (r >= M) continue;
    #pragma unroll
    for (int j = 0; j < 8; j++) {
      const int c = n0 + tn0 + j;
      if (c >= N) continue;
      float v = acc[i][j];
      if (HASBIAS) v += bias[c];
      if (RELU) v = fmaxf(v, 0.f);
      C[(size_t)r * N + c] = v;
    }
  }
}

// ---------------- fused counting-sort infrastructure
__global__ __launch_bounds__(256) void hist2_k(
    const int* __restrict__ edst, const int* __restrict__ bx,
    int* __restrict__ ehist, int* __restrict__ nhist)
{
  int i = blockIdx.x * 256 + threadIdx.x;
  if (i < NEDGE) { atomicAdd(&ehist[edst[i]], 1); return; }
  i -= NEDGE;
  if (i < NNODE) atomicAdd(&nhist[bx[i]], 1);
}

__global__ __launch_bounds__(256) void scan1_k(
    const int* __restrict__ ehist, int* __restrict__ ebase, int* __restrict__ epart,
    const int* __restrict__ nhist, int* __restrict__ nbase, int* __restrict__ npart)
{
  __shared__ int s[256];
  const int t = threadIdx.x;
  const bool eregion = blockIdx.x < NB_E;
  const int b = eregion ? blockIdx.x : blockIdx.x - NB_E;
  const int n = eregion ? NNODE : N_ENT;
  const int* hist = eregion ? ehist : nhist;
  int* base = eregion ? ebase : nbase;
  int* partial = eregion ? epart : npart;
  const int i0 = b * 1024 + t * 4;
  int v[4];
  #pragma unroll
  for (int j = 0; j < 4; j++) v[j] = (i0 + j < n) ? hist[i0 + j] : 0;
  const int tsum = v[0] + v[1] + v[2] + v[3];
  s[t] = tsum;
  __syncthreads();
  #pragma unroll
  for (int off = 1; off < 256; off <<= 1) {
    int u = (t >= off) ? s[t - off] : 0;
    __syncthreads();
    s[t] += u;
    __syncthreads();
  }
  int run = s[t] - tsum;
  #pragma unroll
  for (int j = 0; j < 4; j++) {
    if (i0 + j < n) base[i0 + j] = run;
    run += v[j];
  }
  if (t == 255) partial[b] = s[255];
}

__global__ __launch_bounds__(256) void scan2_k(
    int* __restrict__ epart, int* __restrict__ ebase_end,
    int* __restrict__ npart, int* __restrict__ nbase_end)
{
  __shared__ int s[256];
  const int t = threadIdx.x;
  const bool eregion = blockIdx.x == 0;
  int* partial = eregion ? epart : npart;
  const int nb = eregion ? NB_E : NB_N;
  const int v = (t < nb) ? partial[t] : 0;
  s[t] = v;
  __syncthreads();
  #pragma unroll
  for (int off = 1; off < 256; off <<= 1) {
    int u = (t >= off) ? s[t - off] : 0;
    __syncthreads();
    s[t] += u;
    __syncthreads();
  }
  if (t < nb) partial[t] = s[t] - v;
  if (t == 255) *(eregion ? ebase_end : nbase_end) = s[255];
}

#define NB3_E 469  // ceil(NNODE/256)
__global__ __launch_bounds__(256) void scan3_k(
    int* __restrict__ ebase, const int* __restrict__ epart,
    int* __restrict__ nbase, const int* __restrict__ npart)
{
  if (blockIdx.x < NB3_E) {
    int i = blockIdx.x * 256 + threadIdx.x;
    if (i < NNODE) ebase[i] += epart[i >> 10];
  } else {
    int i = (blockIdx.x - NB3_E) * 256 + threadIdx.x;
    if (i < N_ENT) nbase[i] += npart[i >> 10];
  }
}

__global__ __launch_bounds__(256) void scatter2_k(
    const int* __restrict__ esrc, const int* __restrict__ edst, const float* __restrict__ ew,
    const int* __restrict__ bx, const int* __restrict__ bg,
    const int* __restrict__ ebase, int* __restrict__ ecur,
    float* __restrict__ s_w, int* __restrict__ s_src,
    int* __restrict__ s_en, int* __restrict__ s_gn,
    const int* __restrict__ nbase, int* __restrict__ ncur, int* __restrict__ node_of)
{
  int i = blockIdx.x * 256 + threadIdx.x;
  if (i < NEDGE) {
    int d = edst[i];
    int p = ebase[d] + atomicAdd(&ecur[d], 1);
    int s = esrc[i];
    s_w[p] = ew[i];
    s_src[p] = s;
    s_en[p] = bx[s];
    s_gn[p] = bg[s];
    return;
  }
  i -= NEDGE;
  if (i < NNODE) {
    int ent = bx[i];
    int p = nbase[ent] + atomicAdd(&ncur[ent], 1);
    node_of[p] = i;
  }
}

// ---------------- GCN layer 1 gather (bf16 table)
__global__ __launch_bounds__(256) void spmm1_g(
    const int* __restrict__ ebase, const float* __restrict__ s_w,
    const int* __restrict__ s_en, const int* __restrict__ s_gn,
    const unsigned short* __restrict__ egr1,
    const float* __restrict__ b_g1, unsigned short* __restrict__ h1)
{
  const int gid = blockIdx.x * blockDim.x + threadIdx.x;
  const int d = gid >> 6, lane = gid & 63;
  if (d >= NNODE) return;
  const int p0 = ebase[d], p1 = ebase[d + 1];
  float acc[4] = {0.f, 0.f, 0.f, 0.f};
  for (int p = p0; p < p1; ++p) {
    const float w = s_w[p];
    const int en = s_en[p], gn = s_gn[p];
    const ushort4 va = *(const ushort4*)(egr1 + (size_t)en * 256 + lane * 4);
    const ushort4 vb = *(const ushort4*)(egr1 + (size_t)(N_ENT + gn) * 256 + lane * 4);
    acc[0] += w * (bf2f(va.x) + bf2f(vb.x));
    acc[1] += w * (bf2f(va.y) + bf2f(vb.y));
    acc[2] += w * (bf2f(va.z) + bf2f(vb.z));
    acc[3] += w * (bf2f(va.w) + bf2f(vb.w));
  }
  const float4 b = ((const float4*)b_g1)[lane];
  ushort4 o;
  o.x = f2bf(fmaxf(acc[0] + b.x, 0.f));
  o.y = f2bf(fmaxf(acc[1] + b.y, 0.f));
  o.z = f2bf(fmaxf(acc[2] + b.z, 0.f));
  o.w = f2bf(fmaxf(acc[3] + b.w, 0.f));
  *(ushort4*)(h1 + (size_t)d * 256 + lane * 4) = o;
}

// ---------------- GCN layer 2 gather + bias + fused score; h2 bf16
__global__ __launch_bounds__(256) void spmm2_g(
    const int* __restrict__ ebase, const float* __restrict__ s_w,
    const int* __restrict__ s_src, const unsigned short* __restrict__ hg2,
    const float* __restrict__ b_g2, const float* __restrict__ W_e,
    unsigned short* __restrict__ h2, float* __restrict__ score)
{
  const int gid = blockIdx.x * blockDim.x + threadIdx.x;
  const int d = gid >> 6, lane = gid & 63;
  if (d >= NNODE) return;
  const int p0 = ebase[d], p1 = ebase[d + 1];
  float acc[4] = {0.f, 0.f, 0.f, 0.f};
  const int col = lane * 4;
  float sp = 0.f;
  if (lane < 50) {
    for (int p = p0; p < p1; ++p) {
      const float w = s_w[p];
      const ushort4 v = *(const ushort4*)(hg2 + (size_t)s_src[p] * 208 + col);
      acc[0] += w * bf2f(v.x); acc[1] += w * bf2f(v.y);
      acc[2] += w * bf2f(v.z); acc[3] += w * bf2f(v.w);
    }
    const float4 b = ((const float4*)b_g2)[lane];
    acc[0] += b.x; acc[1] += b.y; acc[2] += b.z; acc[3] += b.w;
    ushort4 o;
    o.x = f2bf(acc[0]); o.y = f2bf(acc[1]); o.z = f2bf(acc[2]); o.w = f2bf(acc[3]);
    *(ushort4*)(h2 + (size_t)d * 200 + col) = o;
    const float4 we = ((const float4*)W_e)[lane];
    sp = acc[0] * we.x + acc[1] * we.y + acc[2] * we.z + acc[3] * we.w;
  }
  #pragma unroll
  for (int off = 32; off; off >>= 1) sp += __shfl_xor(sp, off);
  if (lane == 0) score[d] = sp;
}

// ---------------- per-entity softmax + weighted sum + mean -> embA bf16 [14976][416]
__global__ __launch_bounds__(256) void ent_k(
    const int* __restrict__ nbase, const int* __restrict__ node_of,
    const unsigned short* __restrict__ h2, const float* __restrict__ score,
    unsigned short* __restrict__ embA)
{
  const int gid = blockIdx.x * blockDim.x + threadIdx.x;
  const int ent = gid >> 6, lane = gid & 63;
  if (ent >= N_ENT) return;
  const int p0 = nbase[ent], p1 = nbase[ent + 1];
  const int cnt = p1 - p0;
  float m = -3.4e38f;
  for (int p = p0 + lane; p < p1; p += 64) m = fmaxf(m, score[node_of[p]]);
  #pragma unroll
  for (int off = 32; off; off >>= 1) m = fmaxf(m, __shfl_xor(m, off));
  float es = 0.f;
  for (int p = p0 + lane; p < p1; p += 64) es += __expf(score[node_of[p]] - m);
  #pragma unroll
  for (int off = 32; off; off >>= 1) es += __shfl_xor(es, off);
  const float inv_es = (cnt > 0) ? 1.f / es : 0.f;
  const float inv_cnt = 1.f / fmaxf((float)cnt, 1.f);
  float aw[4] = {0.f, 0.f, 0.f, 0.f};
  float am[4] = {0.f, 0.f, 0.f, 0.f};
  for (int p = p0; p < p1; ++p) {
    const int nd = node_of[p];
    const float z = __expf(score[nd] - m) * inv_es;
    if (lane < 50) {
      const ushort4 v = *(const ushort4*)(h2 + (size_t)nd * 200 + lane * 4);
      const float vx = bf2f(v.x), vy = bf2f(v.y), vz = bf2f(v.z), vw = bf2f(v.w);
      aw[0] += z * vx; aw[1] += z * vy; aw[2] += z * vz; aw[3] += z * vw;
      am[0] += vx; am[1] += vy; am[2] += vz; am[3] += vw;
    }
  }
  if (lane < 50) {
    ushort4 ow, om;
    ow.x = f2bf(aw[0]); ow.y = f2bf(aw[1]); ow.z = f2bf(aw[2]); ow.w = f2bf(aw[3]);
    om.x = f2bf(am[0] * inv_cnt); om.y = f2bf(am[1] * inv_cnt);
    om.z = f2bf(am[2] * inv_cnt); om.w = f2bf(am[3] * inv_cnt);
    *(ushort4*)(embA + (size_t)ent * 416 + lane * 4) = ow;
    *(ushort4*)(embA + (size_t)ent * 416 + 200 + lane * 4) = om;
  }
}

extern "C" void kernel_launch(void* const* d_in, const int* in_sizes, int n_in,
                              void* d_out, int out_size, void* d_ws, size_t ws_size,
                              hipStream_t stream)
{
  const float* img  = (const float*)d_in[0];
  const float* txt  = (const float*)d_in[1];
  const float* rel  = (const float*)d_in[2];
  const float* W_it = (const float*)d_in[3];
  const float* b_it = (const float*)d_in[4];
  const float* W_ri = (const float*)d_in[5];
  const float* b_ri = (const float*)d_in[6];
  const float* W_g1 = (const float*)d_in[7];
  const float* b_g1 = (const float*)d_in[8];
  const float* W_g2 = (const float*)d_in[9];
  const float* b_g2 = (const float*)d_in[10];
  const float* W_e  = (const float*)d_in[11];
  const float* W_eo = (const float*)d_in[13];
  const float* b_eo = (const float*)d_in[14];
  const float* W_r  = (const float*)d_in[15];
  const float* b_r  = (const float*)d_in[16];
  const float* ew   = (const float*)d_in[17];
  const int*   bx   = (const int*)d_in[18];
  const int*   bg   = (const int*)d_in[19];
  const int*   esrc = (const int*)d_in[20];
  const int*   edst = (const int*)d_in[21];

  float* ws = (float*)d_ws;
  size_t off = 0;
  auto alloc = [&](size_t n){ size_t r = off; off += (n + 255) & ~(size_t)255; return r; };
  unsigned short* feat1 = (unsigned short*)(ws + alloc((size_t)MROWS1 * 224 / 2));
  unsigned short* egr1  = (unsigned short*)(ws + alloc((size_t)MROWS1 * 256 / 2));
  unsigned short* h1    = (unsigned short*)(ws + alloc((size_t)NNODE * 256 / 2));
  unsigned short* hg2   = (unsigned short*)(ws + alloc((size_t)NNODE * 208 / 2));
  unsigned short* embA  = (unsigned short*)(ws + alloc((size_t)MP_ENC * 416 / 2));
  unsigned short* h2    = (unsigned short*)(ws + alloc((size_t)NNODE * 200 / 2));
  float* part  = ws + alloc((size_t)ENC_SPLIT * MP_ENC * NP_ENC);
  float* rin   = ws + alloc((size_t)N_REL * 100);
  float* score = ws + alloc(NNODE);
  size_t cnt0 = alloc((size_t)NNODE * 2 + (size_t)N_ENT * 2);
  int* ehist = (int*)(ws + cnt0);
  int* ecur  = ehist + NNODE;
  int* nhist = ecur + NNODE;
  int* ncur  = nhist + N_ENT;
  int* ebase = (int*)(ws + alloc(NNODE + 1));
  int* nbase = (int*)(ws + alloc(N_ENT + 1));
  int* epart = (int*)(ws + alloc(256));
  int* npart = (int*)(ws + alloc(256));
  float* s_w  = ws + alloc(NEDGE);
  int* s_src  = (int*)(ws + alloc(NEDGE));
  int* s_en   = (int*)(ws + alloc(NEDGE));
  int* s_gn   = (int*)(ws + alloc(NEDGE));
  int* node_of = (int*)(ws + alloc(NNODE));
  unsigned short* Wt1  = (unsigned short*)(ws + alloc((size_t)NP_ENC * KP_ENC / 2));
  unsigned short* Wtg1 = (unsigned short*)(ws + alloc((size_t)256 * 224 / 2));
  unsigned short* Wt2  = (unsigned short*)(ws + alloc((size_t)208 * 256 / 2));
  unsigned short* Wteo = (unsigned short*)(ws + alloc((size_t)208 * 416 / 2));

  dim3 blk(256);

  // ---- memsets
  hipMemsetAsync(ehist, 0, ((size_t)NNODE * 2 + (size_t)N_ENT * 2) * 4, stream);
  hipMemsetAsync(feat1, 0, (size_t)MROWS1 * 224 * 2, stream);
  hipMemsetAsync(embA,  0, (size_t)MP_ENC * 416 * 2, stream);

  // ---- CSR build
  hist2_k<<<ceil_div(NEDGE + NNODE, 256), blk, 0, stream>>>(edst, bx, ehist, nhist);
  scan1_k<<<NB_E + NB_N, blk, 0, stream>>>(ehist, ebase, epart, nhist, nbase, npart);
  scan2_k<<<2, blk, 0, stream>>>(epart, ebase + NNODE, npart, nbase + N_ENT);
  scan3_k<<<NB3_E + ceil_div(N_ENT, 256), blk, 0, stream>>>(ebase, epart, nbase, npart);
  scatter2_k<<<ceil_div(NEDGE + NNODE, 256), blk, 0, stream>>>(
      esrc, edst, ew, bx, bg, ebase, ecur, s_w, s_src, s_en, s_gn, nbase, ncur, node_of);

  // ---- weight prep (fused)
  wt_all_k<<<ceil_div(NP_ENC * KP_ENC + 256 * 224 + 208 * 256 + 208 * 416, 256), blk, 0, stream>>>(
      W_it, W_g1, W_g2, W_eo, Wt1, Wtg1, Wt2, Wteo);

  // ---- encoders
  enc_mfma<<<dim3(MP_ENC / 64, ENC_SPLIT), blk, 0, stream>>>(img, txt, Wt1, part);
  enc_reduce<<<ceil_div(N_ENT * 100, 256), blk, 0, stream>>>(part, b_it, feat1);
  gemm_f32<true, true><<<dim3(1, ceil_div(N_REL, 64)), blk, 0, stream>>>(
      rel, 300, rel, W_ri, b_ri, rin, N_REL, 300, 100);
  rin_pack<<<ceil_div(N_REL * 100, 256), blk, 0, stream>>>(rin, feat1);

  // ---- combined table + GCN layer 1 gather
  egr1_mfma<<<MROWS1 / 64, blk, 0, stream>>>(feat1, Wtg1, egr1);
  spmm1_g<<<ceil_div(NNODE * 64, 256), blk, 0, stream>>>(
      ebase, s_w, s_en, s_gn, egr1, b_g1, h1);

  // ---- GCN layer 2
  gemm2_mfma<<<NNODE / 64, blk, 0, stream>>>(h1, Wt2, hg2);
  spmm2_g<<<ceil_div(NNODE * 64, 256), blk, 0, stream>>>(
      ebase, s_w, s_src, hg2, b_g2, W_e, h2, score);

  // ---- per-entity softmax + weighted sum + mean -> embA (bf16)
  ent_k<<<ceil_div(N_ENT * 64, 256), blk, 0, stream>>>(nbase, node_of, h2, score, embA);

  // ---- final projections
  float* out_new = (float*)d_out;
  float* out_rel = out_new + (size_t)N_ENT * 200;
  fin_mfma<<<MP_ENC / 64, blk, 0, stream>>>(embA, Wteo, b_eo, out_new);
  gemm_f32<true, true><<<dim3(2, ceil_div(N_REL, 64)), blk, 0, stream>>>(
      rel, 300, rel, W_r, b_r, out_rel, N_REL, 300, 200);
}

// Round 10
// 628.959 us; speedup vs baseline: 1.2286x; 1.0778x over previous
//
#include <hip/hip_runtime.h>

#define N_ENT 14951
#define N_REL 1345
#define NNODE 120000
#define NEDGE 480000
#define MP_ENC 14976    // 234*64
#define KP_ENC 4608     // 16*288 >= 4396
#define NP_ENC 112
#define ENC_SPLIT 16
#define ENC_KSPLIT 288
#define ENC_STEPS 9     // 288/32
#define MROWS1 16320    // 255*64 >= N_ENT+N_REL
#define NB_E 118        // ceil(NNODE/1024)
#define NB_N 15         // ceil(N_ENT/1024)

static inline int ceil_div(int a, int b){ return (a + b - 1) / b; }

typedef __bf16 bf16x8 __attribute__((ext_vector_type(8)));
typedef float f32x4 __attribute__((ext_vector_type(4)));

__device__ inline unsigned short f2bf(float f){
  unsigned u = __float_as_uint(f);
  return (unsigned short)((u + 0x7fffu + ((u >> 16) & 1u)) >> 16);
}
__device__ inline float bf2f(unsigned short b){
  return __uint_as_float(((unsigned)b) << 16);
}

// ---------------- bf16 MFMA encoder GEMM, R6 staged structure, split-K=16
__global__ __launch_bounds__(256) void enc_mfma(
    const float* __restrict__ img, const float* __restrict__ txt,
    const unsigned short* __restrict__ Wt1, float* __restrict__ part)
{
  __shared__ unsigned short As[64 * 40];
  __shared__ unsigned short Bs[112 * 40];
  const int t = threadIdx.x;
  const int m0 = blockIdx.x * 64;
  const int s = blockIdx.y;
  const int l = t & 63, w = t >> 6;
  f32x4 acc[7];
  #pragma unroll
  for (int i = 0; i < 7; i++) acc[i] = f32x4{0.f, 0.f, 0.f, 0.f};

  for (int step = 0; step < ENC_STEPS; ++step) {
    const int kb = s * ENC_KSPLIT + step * 32;
    #pragma unroll
    for (int p = 0; p < 2; ++p) {
      const int c = t + p * 256;
      const int row = c >> 3, kq = c & 7;
      const int rowg = m0 + row;
      const int k = kb + kq * 4;
      float4 v = make_float4(0.f, 0.f, 0.f, 0.f);
      if (rowg < N_ENT) {
        if (k < 4096)      v = *(const float4*)(img + (size_t)rowg * 4096 + k);
        else if (k < 4396) v = *(const float4*)(txt + (size_t)rowg * 300 + (k - 4096));
      }
      ushort4 b;
      b.x = f2bf(v.x); b.y = f2bf(v.y); b.z = f2bf(v.z); b.w = f2bf(v.w);
      *(ushort4*)&As[row * 40 + kq * 4] = b;
    }
    {
      const int n = t >> 2, k16 = t & 3;
      *(uint4*)&Bs[n * 40 + k16 * 8] = *(const uint4*)(Wt1 + (size_t)n * KP_ENC + kb + k16 * 8);
      if (t < 192) {
        const int c = t + 256;
        const int n2 = c >> 2, k2 = c & 3;
        *(uint4*)&Bs[n2 * 40 + k2 * 8] = *(const uint4*)(Wt1 + (size_t)n2 * KP_ENC + kb + k2 * 8);
      }
    }
    __syncthreads();
    bf16x8 a = *(const bf16x8*)&As[(w * 16 + (l & 15)) * 40 + (l >> 4) * 8];
    #pragma unroll
    for (int ct = 0; ct < 7; ++ct) {
      bf16x8 bb = *(const bf16x8*)&Bs[(ct * 16 + (l & 15)) * 40 + (l >> 4) * 8];
      acc[ct] = __builtin_amdgcn_mfma_f32_16x16x32_bf16(a, bb, acc[ct], 0, 0, 0);
    }
    __syncthreads();
  }
  const int rb = m0 + w * 16 + (l >> 4) * 4;
  const int col = l & 15;
  float* pp = part + (size_t)s * MP_ENC * NP_ENC;
  #pragma unroll
  for (int ct = 0; ct < 7; ++ct)
    #pragma unroll
    for (int i = 0; i < 4; ++i)
      pp[(size_t)(rb + i) * NP_ENC + ct * 16 + col] = acc[ct][i];
}

// reduce split-K partials + bias -> feat1 rows [0,N_ENT) cols [0,100), bf16
__global__ __launch_bounds__(256) void enc_reduce(
    const float* __restrict__ part, const float* __restrict__ bias,
    unsigned short* __restrict__ feat1)
{
  int i = blockIdx.x * 256 + threadIdx.x;
  if (i >= N_ENT * 100) return;
  int r = i / 100, c = i % 100;
  float v = bias[c];
  #pragma unroll
  for (int s = 0; s < ENC_SPLIT; ++s) v += part[((size_t)s * MP_ENC + r) * NP_ENC + c];
  feat1[(size_t)r * 224 + c] = f2bf(v);
}

// pack rin -> feat1 rows [N_ENT, N_ENT+N_REL) cols [100,200)
__global__ __launch_bounds__(256) void rin_pack(
    const float* __restrict__ rin, unsigned short* __restrict__ feat1)
{
  int i = blockIdx.x * 256 + threadIdx.x;
  if (i >= N_REL * 100) return;
  int r = i / 100, c = i % 100;
  feat1[(size_t)(N_ENT + r) * 224 + 100 + c] = f2bf(rin[i]);
}

// ---------------- egr1 = feat1[MROWS1,224] @ Wtg1^T -> bf16 [MROWS1,256]
__global__ __launch_bounds__(256) void egr1_mfma(
    const unsigned short* __restrict__ feat1, const unsigned short* __restrict__ Wtg1,
    unsigned short* __restrict__ egr1)
{
  __shared__ unsigned short As[64 * 40];
  __shared__ unsigned short Bs[256 * 40];
  const int t = threadIdx.x;
  const int m0 = blockIdx.x * 64;
  const int l = t & 63, w = t >> 6;
  f32x4 acc[16];
  #pragma unroll
  for (int i = 0; i < 16; i++) acc[i] = f32x4{0.f, 0.f, 0.f, 0.f};

  for (int step = 0; step < 7; ++step) {
    const int kb = step * 32;
    {
      const int row = t >> 2, kc = t & 3;
      *(uint4*)&As[row * 40 + kc * 8] = *(const uint4*)(feat1 + (size_t)(m0 + row) * 224 + kb + kc * 8);
    }
    #pragma unroll
    for (int p = 0; p < 4; ++p) {
      const int c = t + p * 256;
      const int n = c >> 2, k16 = c & 3;
      *(uint4*)&Bs[n * 40 + k16 * 8] = *(const uint4*)(Wtg1 + (size_t)n * 224 + kb + k16 * 8);
    }
    __syncthreads();
    bf16x8 a = *(const bf16x8*)&As[(w * 16 + (l & 15)) * 40 + (l >> 4) * 8];
    #pragma unroll
    for (int ct = 0; ct < 16; ++ct) {
      bf16x8 bb = *(const bf16x8*)&Bs[(ct * 16 + (l & 15)) * 40 + (l >> 4) * 8];
      acc[ct] = __builtin_amdgcn_mfma_f32_16x16x32_bf16(a, bb, acc[ct], 0, 0, 0);
    }
    __syncthreads();
  }
  const int rb = m0 + w * 16 + (l >> 4) * 4;
  const int col0 = l & 15;
  #pragma unroll
  for (int ct = 0; ct < 16; ++ct) {
    const int col = ct * 16 + col0;
    #pragma unroll
    for (int i = 0; i < 4; ++i)
      egr1[(size_t)(rb + i) * 256 + col] = f2bf(acc[ct][i]);
  }
}

// ---------------- hg2 = h1[NNODE,256](bf16) @ Wt2^T -> bf16 [NNODE,208]
__global__ __launch_bounds__(256) void gemm2_mfma(
    const unsigned short* __restrict__ h1, const unsigned short* __restrict__ Wt2,
    unsigned short* __restrict__ hg2)
{
  __shared__ unsigned short As[64 * 40];
  __shared__ unsigned short Bs[208 * 40];
  const int t = threadIdx.x;
  const int m0 = blockIdx.x * 64;
  const int l = t & 63, w = t >> 6;
  f32x4 acc[13];
  #pragma unroll
  for (int i = 0; i < 13; i++) acc[i] = f32x4{0.f, 0.f, 0.f, 0.f};

  for (int step = 0; step < 8; ++step) {
    const int kb = step * 32;
    {
      const int row = t >> 2, kc = t & 3;
      *(uint4*)&As[row * 40 + kc * 8] = *(const uint4*)(h1 + (size_t)(m0 + row) * 256 + kb + kc * 8);
    }
    #pragma unroll
    for (int p = 0; p < 4; ++p) {
      const int c = t + p * 256;
      if (c < 832) {
        const int n = c >> 2, k16 = c & 3;
        *(uint4*)&Bs[n * 40 + k16 * 8] = *(const uint4*)(Wt2 + (size_t)n * 256 + kb + k16 * 8);
      }
    }
    __syncthreads();
    bf16x8 a = *(const bf16x8*)&As[(w * 16 + (l & 15)) * 40 + (l >> 4) * 8];
    #pragma unroll
    for (int ct = 0; ct < 13; ++ct) {
      bf16x8 bb = *(const bf16x8*)&Bs[(ct * 16 + (l & 15)) * 40 + (l >> 4) * 8];
      acc[ct] = __builtin_amdgcn_mfma_f32_16x16x32_bf16(a, bb, acc[ct], 0, 0, 0);
    }
    __syncthreads();
  }
  const int rb = m0 + w * 16 + (l >> 4) * 4;
  const int col0 = l & 15;
  #pragma unroll
  for (int ct = 0; ct < 13; ++ct) {
    const int col = ct * 16 + col0;
    #pragma unroll
    for (int i = 0; i < 4; ++i)
      hg2[(size_t)(rb + i) * 208 + col] = f2bf(acc[ct][i]);
  }
}

// ---------------- out_new = embA[14976,416](bf16) @ Wteo^T + b_eo
__global__ __launch_bounds__(256) void fin_mfma(
    const unsigned short* __restrict__ embA, const unsigned short* __restrict__ Wteo,
    const float* __restrict__ b_eo, float* __restrict__ out)
{
  __shared__ unsigned short As[64 * 40];
  __shared__ unsigned short Bs[208 * 40];
  const int t = threadIdx.x;
  const int m0 = blockIdx.x * 64;
  const int l = t & 63, w = t >> 6;
  f32x4 acc[13];
  #pragma unroll
  for (int i = 0; i < 13; i++) acc[i] = f32x4{0.f, 0.f, 0.f, 0.f};

  for (int step = 0; step < 13; ++step) {
    const int kb = step * 32;
    {
      const int row = t >> 2, kc = t & 3;
      *(uint4*)&As[row * 40 + kc * 8] = *(const uint4*)(embA + (size_t)(m0 + row) * 416 + kb + kc * 8);
    }
    #pragma unroll
    for (int p = 0; p < 4; ++p) {
      const int c = t + p * 256;
      if (c < 832) {
        const int n = c >> 2, k16 = c & 3;
        *(uint4*)&Bs[n * 40 + k16 * 8] = *(const uint4*)(Wteo + (size_t)n * 416 + kb + k16 * 8);
      }
    }
    __syncthreads();
    bf16x8 a = *(const bf16x8*)&As[(w * 16 + (l & 15)) * 40 + (l >> 4) * 8];
    #pragma unroll
    for (int ct = 0; ct < 13; ++ct) {
      bf16x8 bb = *(const bf16x8*)&Bs[(ct * 16 + (l & 15)) * 40 + (l >> 4) * 8];
      acc[ct] = __builtin_amdgcn_mfma_f32_16x16x32_bf16(a, bb, acc[ct], 0, 0, 0);
    }
    __syncthreads();
  }
  const int rb = m0 + w * 16 + (l >> 4) * 4;
  const int col0 = l & 15;
  #pragma unroll
  for (int ct = 0; ct < 13; ++ct) {
    const int col = ct * 16 + col0;
    if (col < 200) {
      const float b = b_eo[col];
      #pragma unroll
      for (int i = 0; i < 4; ++i) {
        const int r = rb + i;
        if (r < N_ENT) out[(size_t)r * 200 + col] = acc[ct][i] + b;
      }
    }
  }
}

// ---------------- fused weight prep: Wt1(enc), Wtg1, Wt2, Wteo
__global__ __launch_bounds__(256) void wt_all_k(
    const float* __restrict__ W_it, const float* __restrict__ W_g1,
    const float* __restrict__ W_g2, const float* __restrict__ W_eo,
    unsigned short* __restrict__ Wt1, unsigned short* __restrict__ Wtg1,
    unsigned short* __restrict__ Wt2, unsigned short* __restrict__ Wteo)
{
  int i = blockIdx.x * 256 + threadIdx.x;
  if (i < NP_ENC * KP_ENC) {
    int n = i / KP_ENC, k = i % KP_ENC;
    float v = (n < 100 && k < 4396) ? W_it[(size_t)k * 100 + n] : 0.f;
    Wt1[i] = f2bf(v);
    return;
  }
  i -= NP_ENC * KP_ENC;
  if (i < 256 * 224) {
    int n = i / 224, k = i % 224;
    float v = (k < 200) ? W_g1[(size_t)k * 256 + n] : 0.f;
    Wtg1[i] = f2bf(v);
    return;
  }
  i -= 256 * 224;
  if (i < 208 * 256) {
    int n = i >> 8, k = i & 255;
    float v = (n < 200) ? W_g2[(size_t)k * 200 + n] : 0.f;
    Wt2[i] = f2bf(v);
    return;
  }
  i -= 208 * 256;
  if (i < 208 * 416) {
    int n = i / 416, k = i % 416;
    float v = (n < 200 && k < 400) ? W_eo[(size_t)k * 200 + n] : 0.f;
    Wteo[i] = f2bf(v);
  }
}

// ---------------- generic f32 GEMM (small: relation encoders only)
template<bool RELU, bool HASBIAS>
__global__ __launch_bounds__(256) void gemm_f32(
    const float* __restrict__ A1, int K1, const float* __restrict__ A2,
    const float* __restrict__ B, const float* __restrict__ bias,
    float* __restrict__ C, int M, int K, int N)
{
  constexpr int BM = 64, BN = 128, BK = 16;
  __shared__ float As[BK][BM + 4];
  __shared__ float Bs[BK][BN];
  const int t = threadIdx.x;
  const int m0 = blockIdx.y * BM, n0 = blockIdx.x * BN;
  const int tr = t >> 4, tc = t & 15;
  const int tm0 = tr * 4, tn0 = tc * 8;
  const int K2 = K - K1;
  const int arow = t >> 2, aq = (t & 3) * 4;
  const int brow = t >> 4, bc0 = (t & 15) * 4;
  float acc[4][8];
  #pragma unroll
  for (int i = 0; i < 4; i++)
    #pragma unroll
    for (int j = 0; j < 8; j++) acc[i][j] = 0.f;

  for (int k0 = 0; k0 < K; k0 += BK) {
    {
      const int r = m0 + arow;
      const int k = k0 + aq;
      float4 v = make_float4(0.f, 0.f, 0.f, 0.f);
      if (r < M) {
        if (k + 3 < K1) {
          v = *(const float4*)(A1 + (size_t)r * K1 + k);
        } else if (k >= K1 && (k - K1) + 3 < K2) {
          v = *(const float4*)(A2 + (size_t)r * K2 + (k - K1));
        } else {
          float tmp[4] = {0.f, 0.f, 0.f, 0.f};
          #pragma unroll
          for (int j = 0; j < 4; j++) {
            int kj = k + j;
            if (kj < K) tmp[j] = (kj < K1) ? A1[(size_t)r * K1 + kj]
                                           : A2[(size_t)r * K2 + (kj - K1)];
          }
          v = make_float4(tmp[0], tmp[1], tmp[2], tmp[3]);
        }
      }
      As[aq + 0][arow] = v.x; As[aq + 1][arow] = v.y;
      As[aq + 2][arow] = v.z; As[aq + 3][arow] = v.w;
    }
    {
      const int k = k0 + brow;
      #pragma unroll
      for (int h = 0; h < 2; h++) {
        const int n = n0 + bc0 + h * 64;
        float4 v = make_float4(0.f, 0.f, 0.f, 0.f);
        if (k < K) {
          if (n + 3 < N) {
            v = *(const float4*)(B + (size_t)k * N + n);
          } else {
            float tmp[4] = {0.f, 0.f, 0.f, 0.f};
            for (int j = 0; j < 4; j++) if (n + j < N) tmp[j] = B[(size_t)k * N + n + j];
            v = make_float4(tmp[0], tmp[1], tmp[2], tmp[3]);
          }
        }
        *(float4*)&Bs[brow][bc0 + h * 64] = v;
      }
    }
    __syncthreads();
    #pragma unroll
    for (int k = 0; k < BK; k++) {
      float a[4], b[8];
      *(float4*)&a[0] = *(const float4*)&As[k][tm0];
      *(float4*)&b[0] = *(const float4*)&Bs[k][tn0];
      *(float4*)&b[4] = *(const float4*)&Bs[k][tn0 + 4];
      #pragma unroll
      for (int i = 0; i < 4; i++)
        #pragma unroll
        for (int j = 0; j < 8; j++) acc[i][j] = fmaf(a[i], b[j], acc[i][j]);
    }
    __syncthreads();
  }
  #pragma unroll
  for (int i = 0; i < 4; i++) {
    const int r = m0 + tm0 + i;
    if (r >= M) continue;
    #pragma unroll
    for (int j = 0; j < 8; j++) {
      const int c = n0 + tn0 + j;
      if (c >= N) continue;
      float v = acc[i][j];
      if (HASBIAS) v += bias[c];
      if (RELU) v = fmaxf(v, 0.f);
      C[(size_t)r * N + c] = v;
    }
  }
}

// ---------------- fused counting-sort infrastructure
__global__ __launch_bounds__(256) void hist2_k(
    const int* __restrict__ edst, const int* __restrict__ bx,
    int* __restrict__ ehist, int* __restrict__ nhist)
{
  int i = blockIdx.x * 256 + threadIdx.x;
  if (i < NEDGE) { atomicAdd(&ehist[edst[i]], 1); return; }
  i -= NEDGE;
  if (i < NNODE) atomicAdd(&nhist[bx[i]], 1);
}

__global__ __launch_bounds__(256) void scan1_k(
    const int* __restrict__ ehist, int* __restrict__ ebase, int* __restrict__ epart,
    const int* __restrict__ nhist, int* __restrict__ nbase, int* __restrict__ npart)
{
  __shared__ int s[256];
  const int t = threadIdx.x;
  const bool eregion = blockIdx.x < NB_E;
  const int b = eregion ? blockIdx.x : blockIdx.x - NB_E;
  const int n = eregion ? NNODE : N_ENT;
  const int* hist = eregion ? ehist : nhist;
  int* base = eregion ? ebase : nbase;
  int* partial = eregion ? epart : npart;
  const int i0 = b * 1024 + t * 4;
  int v[4];
  #pragma unroll
  for (int j = 0; j < 4; j++) v[j] = (i0 + j < n) ? hist[i0 + j] : 0;
  const int tsum = v[0] + v[1] + v[2] + v[3];
  s[t] = tsum;
  __syncthreads();
  #pragma unroll
  for (int off = 1; off < 256; off <<= 1) {
    int u = (t >= off) ? s[t - off] : 0;
    __syncthreads();
    s[t] += u;
    __syncthreads();
  }
  int run = s[t] - tsum;
  #pragma unroll
  for (int j = 0; j < 4; j++) {
    if (i0 + j < n) base[i0 + j] = run;
    run += v[j];
  }
  if (t == 255) partial[b] = s[255];
}

__global__ __launch_bounds__(256) void scan2_k(
    int* __restrict__ epart, int* __restrict__ ebase_end,
    int* __restrict__ npart, int* __restrict__ nbase_end)
{
  __shared__ int s[256];
  const int t = threadIdx.x;
  const bool eregion = blockIdx.x == 0;
  int* partial = eregion ? epart : npart;
  const int nb = eregion ? NB_E : NB_N;
  const int v = (t < nb) ? partial[t] : 0;
  s[t] = v;
  __syncthreads();
  #pragma unroll
  for (int off = 1; off < 256; off <<= 1) {
    int u = (t >= off) ? s[t - off] : 0;
    __syncthreads();
    s[t] += u;
    __syncthreads();
  }
  if (t < nb) partial[t] = s[t] - v;
  if (t == 255) *(eregion ? ebase_end : nbase_end) = s[255];
}

#define NB3_E 469  // ceil(NNODE/256)
__global__ __launch_bounds__(256) void scan3_k(
    int* __restrict__ ebase, const int* __restrict__ epart,
    int* __restrict__ nbase, const int* __restrict__ npart)
{
  if (blockIdx.x < NB3_E) {
    int i = blockIdx.x * 256 + threadIdx.x;
    if (i < NNODE) ebase[i] += epart[i >> 10];
  } else {
    int i = (blockIdx.x - NB3_E) * 256 + threadIdx.x;
    if (i < N_ENT) nbase[i] += npart[i >> 10];
  }
}

__global__ __launch_bounds__(256) void scatter2_k(
    const int* __restrict__ esrc, const int* __restrict__ edst, const float* __restrict__ ew,
    const int* __restrict__ bx, const int* __restrict__ bg,
    const int* __restrict__ ebase, int* __restrict__ ecur,
    float* __restrict__ s_w, int* __restrict__ s_src,
    int* __restrict__ s_en, int* __restrict__ s_gn,
    const int* __restrict__ nbase, int* __restrict__ ncur, int* __restrict__ node_of)
{
  int i = blockIdx.x * 256 + threadIdx.x;
  if (i < NEDGE) {
    int d = edst[i];
    int p = ebase[d] + atomicAdd(&ecur[d], 1);
    int s = esrc[i];
    s_w[p] = ew[i];
    s_src[p] = s;
    s_en[p] = bx[s];
    s_gn[p] = bg[s];
    return;
  }
  i -= NEDGE;
  if (i < NNODE) {
    int ent = bx[i];
    int p = nbase[ent] + atomicAdd(&ncur[ent], 1);
    node_of[p] = i;
  }
}

// ---------------- GCN layer 1 gather (bf16 table)
__global__ __launch_bounds__(256) void spmm1_g(
    const int* __restrict__ ebase, const float* __restrict__ s_w,
    const int* __restrict__ s_en, const int* __restrict__ s_gn,
    const unsigned short* __restrict__ egr1,
    const float* __restrict__ b_g1, unsigned short* __restrict__ h1)
{
  const int gid = blockIdx.x * blockDim.x + threadIdx.x;
  const int d = gid >> 6, lane = gid & 63;
  if (d >= NNODE) return;
  const int p0 = ebase[d], p1 = ebase[d + 1];
  float acc[4] = {0.f, 0.f, 0.f, 0.f};
  for (int p = p0; p < p1; ++p) {
    const float w = s_w[p];
    const int en = s_en[p], gn = s_gn[p];
    const ushort4 va = *(const ushort4*)(egr1 + (size_t)en * 256 + lane * 4);
    const ushort4 vb = *(const ushort4*)(egr1 + (size_t)(N_ENT + gn) * 256 + lane * 4);
    acc[0] += w * (bf2f(va.x) + bf2f(vb.x));
    acc[1] += w * (bf2f(va.y) + bf2f(vb.y));
    acc[2] += w * (bf2f(va.z) + bf2f(vb.z));
    acc[3] += w * (bf2f(va.w) + bf2f(vb.w));
  }
  const float4 b = ((const float4*)b_g1)[lane];
  ushort4 o;
  o.x = f2bf(fmaxf(acc[0] + b.x, 0.f));
  o.y = f2bf(fmaxf(acc[1] + b.y, 0.f));
  o.z = f2bf(fmaxf(acc[2] + b.z, 0.f));
  o.w = f2bf(fmaxf(acc[3] + b.w, 0.f));
  *(ushort4*)(h1 + (size_t)d * 256 + lane * 4) = o;
}

// ---------------- GCN layer 2 gather + bias + fused score; h2 bf16
__global__ __launch_bounds__(256) void spmm2_g(
    const int* __restrict__ ebase, const float* __restrict__ s_w,
    const int* __restrict__ s_src, const unsigned short* __restrict__ hg2,
    const float* __restrict__ b_g2, const float* __restrict__ W_e,
    unsigned short* __restrict__ h2, float* __restrict__ score)
{
  const int gid = blockIdx.x * blockDim.x + threadIdx.x;
  const int d = gid >> 6, lane = gid & 63;
  if (d >= NNODE) return;
  const int p0 = ebase[d], p1 = ebase[d + 1];
  float acc[4] = {0.f, 0.f, 0.f, 0.f};
  const int col = lane * 4;
  float sp = 0.f;
  if (lane < 50) {
    for (int p = p0; p < p1; ++p) {
      const float w = s_w[p];
      const ushort4 v = *(const ushort4*)(hg2 + (size_t)s_src[p] * 208 + col);
      acc[0] += w * bf2f(v.x); acc[1] += w * bf2f(v.y);
      acc[2] += w * bf2f(v.z); acc[3] += w * bf2f(v.w);
    }
    const float4 b = ((const float4*)b_g2)[lane];
    acc[0] += b.x; acc[1] += b.y; acc[2] += b.z; acc[3] += b.w;
    ushort4 o;
    o.x = f2bf(acc[0]); o.y = f2bf(acc[1]); o.z = f2bf(acc[2]); o.w = f2bf(acc[3]);
    *(ushort4*)(h2 + (size_t)d * 200 + col) = o;
    const float4 we = ((const float4*)W_e)[lane];
    sp = acc[0] * we.x + acc[1] * we.y + acc[2] * we.z + acc[3] * we.w;
  }
  #pragma unroll
  for (int off = 32; off; off >>= 1) sp += __shfl_xor(sp, off);
  if (lane == 0) score[d] = sp;
}

// ---------------- per-entity softmax + weighted sum + mean -> embA bf16 [14976][416]
__global__ __launch_bounds__(256) void ent_k(
    const int* __restrict__ nbase, const int* __restrict__ node_of,
    const unsigned short* __restrict__ h2, const float* __restrict__ score,
    unsigned short* __restrict__ embA)
{
  const int gid = blockIdx.x * blockDim.x + threadIdx.x;
  const int ent = gid >> 6, lane = gid & 63;
  if (ent >= N_ENT) return;
  const int p0 = nbase[ent], p1 = nbase[ent + 1];
  const int cnt = p1 - p0;
  float m = -3.4e38f;
  for (int p = p0 + lane; p < p1; p += 64) m = fmaxf(m, score[node_of[p]]);
  #pragma unroll
  for (int off = 32; off; off >>= 1) m = fmaxf(m, __shfl_xor(m, off));
  float es = 0.f;
  for (int p = p0 + lane; p < p1; p += 64) es += __expf(score[node_of[p]] - m);
  #pragma unroll
  for (int off = 32; off; off >>= 1) es += __shfl_xor(es, off);
  const float inv_es = (cnt > 0) ? 1.f / es : 0.f;
  const float inv_cnt = 1.f / fmaxf((float)cnt, 1.f);
  float aw[4] = {0.f, 0.f, 0.f, 0.f};
  float am[4] = {0.f, 0.f, 0.f, 0.f};
  for (int p = p0; p < p1; ++p) {
    const int nd = node_of[p];
    const float z = __expf(score[nd] - m) * inv_es;
    if (lane < 50) {
      const ushort4 v = *(const ushort4*)(h2 + (size_t)nd * 200 + lane * 4);
      const float vx = bf2f(v.x), vy = bf2f(v.y), vz = bf2f(v.z), vw = bf2f(v.w);
      aw[0] += z * vx; aw[1] += z * vy; aw[2] += z * vz; aw[3] += z * vw;
      am[0] += vx; am[1] += vy; am[2] += vz; am[3] += vw;
    }
  }
  if (lane < 50) {
    ushort4 ow, om;
    ow.x = f2bf(aw[0]); ow.y = f2bf(aw[1]); ow.z = f2bf(aw[2]); ow.w = f2bf(aw[3]);
    om.x = f2bf(am[0] * inv_cnt); om.y = f2bf(am[1] * inv_cnt);
    om.z = f2bf(am[2] * inv_cnt); om.w = f2bf(am[3] * inv_cnt);
    *(ushort4*)(embA + (size_t)ent * 416 + lane * 4) = ow;
    *(ushort4*)(embA + (size_t)ent * 416 + 200 + lane * 4) = om;
  }
}

extern "C" void kernel_launch(void* const* d_in, const int* in_sizes, int n_in,
                              void* d_out, int out_size, void* d_ws, size_t ws_size,
                              hipStream_t stream)
{
  const float* img  = (const float*)d_in[0];
  const float* txt  = (const float*)d_in[1];
  const float* rel  = (const float*)d_in[2];
  const float* W_it = (const float*)d_in[3];
  const float* b_it = (const float*)d_in[4];
  const float* W_ri = (const float*)d_in[5];
  const float* b_ri = (const float*)d_in[6];
  const float* W_g1 = (const float*)d_in[7];
  const float* b_g1 = (const float*)d_in[8];
  const float* W_g2 = (const float*)d_in[9];
  const float* b_g2 = (const float*)d_in[10];
  const float* W_e  = (const float*)d_in[11];
  const float* W_eo = (const float*)d_in[13];
  const float* b_eo = (const float*)d_in[14];
  const float* W_r  = (const float*)d_in[15];
  const float* b_r  = (const float*)d_in[16];
  const float* ew   = (const float*)d_in[17];
  const int*   bx   = (const int*)d_in[18];
  const int*   bg   = (const int*)d_in[19];
  const int*   esrc = (const int*)d_in[20];
  const int*   edst = (const int*)d_in[21];

  float* ws = (float*)d_ws;
  size_t off = 0;
  auto alloc = [&](size_t n){ size_t r = off; off += (n + 255) & ~(size_t)255; return r; };
  unsigned short* feat1 = (unsigned short*)(ws + alloc((size_t)MROWS1 * 224 / 2));
  unsigned short* egr1  = (unsigned short*)(ws + alloc((size_t)MROWS1 * 256 / 2));
  unsigned short* h1    = (unsigned short*)(ws + alloc((size_t)NNODE * 256 / 2));
  unsigned short* hg2   = (unsigned short*)(ws + alloc((size_t)NNODE * 208 / 2));
  unsigned short* embA  = (unsigned short*)(ws + alloc((size_t)MP_ENC * 416 / 2));
  unsigned short* h2    = (unsigned short*)(ws + alloc((size_t)NNODE * 200 / 2));
  float* part  = ws + alloc((size_t)ENC_SPLIT * MP_ENC * NP_ENC);
  float* rin   = ws + alloc((size_t)N_REL * 100);
  float* score = ws + alloc(NNODE);
  size_t cnt0 = alloc((size_t)NNODE * 2 + (size_t)N_ENT * 2);
  int* ehist = (int*)(ws + cnt0);
  int* ecur  = ehist + NNODE;
  int* nhist = ecur + NNODE;
  int* ncur  = nhist + N_ENT;
  int* ebase = (int*)(ws + alloc(NNODE + 1));
  int* nbase = (int*)(ws + alloc(N_ENT + 1));
  int* epart = (int*)(ws + alloc(256));
  int* npart = (int*)(ws + alloc(256));
  float* s_w  = ws + alloc(NEDGE);
  int* s_src  = (int*)(ws + alloc(NEDGE));
  int* s_en   = (int*)(ws + alloc(NEDGE));
  int* s_gn   = (int*)(ws + alloc(NEDGE));
  int* node_of = (int*)(ws + alloc(NNODE));
  unsigned short* Wt1  = (unsigned short*)(ws + alloc((size_t)NP_ENC * KP_ENC / 2));
  unsigned short* Wtg1 = (unsigned short*)(ws + alloc((size_t)256 * 224 / 2));
  unsigned short* Wt2  = (unsigned short*)(ws + alloc((size_t)208 * 256 / 2));
  unsigned short* Wteo = (unsigned short*)(ws + alloc((size_t)208 * 416 / 2));

  dim3 blk(256);

  // ---- memsets
  hipMemsetAsync(ehist, 0, ((size_t)NNODE * 2 + (size_t)N_ENT * 2) * 4, stream);
  hipMemsetAsync(feat1, 0, (size_t)MROWS1 * 224 * 2, stream);
  hipMemsetAsync(embA,  0, (size_t)MP_ENC * 416 * 2, stream);

  // ---- CSR build
  hist2_k<<<ceil_div(NEDGE + NNODE, 256), blk, 0, stream>>>(edst, bx, ehist, nhist);
  scan1_k<<<NB_E + NB_N, blk, 0, stream>>>(ehist, ebase, epart, nhist, nbase, npart);
  scan2_k<<<2, blk, 0, stream>>>(epart, ebase + NNODE, npart, nbase + N_ENT);
  scan3_k<<<NB3_E + ceil_div(N_ENT, 256), blk, 0, stream>>>(ebase, epart, nbase, npart);
  scatter2_k<<<ceil_div(NEDGE + NNODE, 256), blk, 0, stream>>>(
      esrc, edst, ew, bx, bg, ebase, ecur, s_w, s_src, s_en, s_gn, nbase, ncur, node_of);

  // ---- weight prep (fused)
  wt_all_k<<<ceil_div(NP_ENC * KP_ENC + 256 * 224 + 208 * 256 + 208 * 416, 256), blk, 0, stream>>>(
      W_it, W_g1, W_g2, W_eo, Wt1, Wtg1, Wt2, Wteo);

  // ---- encoders
  enc_mfma<<<dim3(MP_ENC / 64, ENC_SPLIT), blk, 0, stream>>>(img, txt, Wt1, part);
  enc_reduce<<<ceil_div(N_ENT * 100, 256), blk, 0, stream>>>(part, b_it, feat1);
  gemm_f32<true, true><<<dim3(1, ceil_div(N_REL, 64)), blk, 0, stream>>>(
      rel, 300, rel, W_ri, b_ri, rin, N_REL, 300, 100);
  rin_pack<<<ceil_div(N_REL * 100, 256), blk, 0, stream>>>(rin, feat1);

  // ---- combined table + GCN layer 1 gather
  egr1_mfma<<<MROWS1 / 64, blk, 0, stream>>>(feat1, Wtg1, egr1);
  spmm1_g<<<ceil_div(NNODE * 64, 256), blk, 0, stream>>>(
      ebase, s_w, s_en, s_gn, egr1, b_g1, h1);

  // ---- GCN layer 2
  gemm2_mfma<<<NNODE / 64, blk, 0, stream>>>(h1, Wt2, hg2);
  spmm2_g<<<ceil_div(NNODE * 64, 256), blk, 0, stream>>>(
      ebase, s_w, s_src, hg2, b_g2, W_e, h2, score);

  // ---- per-entity softmax + weighted sum + mean -> embA (bf16)
  ent_k<<<ceil_div(N_ENT * 64, 256), blk, 0, stream>>>(nbase, node_of, h2, score, embA);

  // ---- final projections
  float* out_new = (float*)d_out;
  float* out_rel = out_new + (size_t)N_ENT * 200;
  fin_mfma<<<MP_ENC / 64, blk, 0, stream>>>(embA, Wteo, b_eo, out_new);
  gemm_f32<true, true><<<dim3(2, ceil_div(N_REL, 64)), blk, 0, stream>>>(
      rel, 300, rel, W_r, b_r, out_rel, N_REL, 300, 200);
}

// Round 11
// 567.763 us; speedup vs baseline: 1.3610x; 1.1078x over previous
//
#include <hip/hip_runtime.h>

#define N_ENT 14951
#define N_REL 1345
#define NNODE 120000
#define NEDGE 480000
#define MP_ENC 14976    // 234*64
#define KP_ENC 4480     // 4*1120 >= 4396
#define NP_ENC 112
#define ENC_SPLIT 4
#define ENC_KSPLIT 1120
#define ENC_STEPS 35    // 1120/32
#define MROWS1 16320    // 255*64 >= N_ENT+N_REL
#define NB_E 118        // ceil(NNODE/1024)
#define NB_N 15         // ceil(N_ENT/1024)

static inline int ceil_div(int a, int b){ return (a + b - 1) / b; }

typedef __bf16 bf16x8 __attribute__((ext_vector_type(8)));
typedef float f32x4 __attribute__((ext_vector_type(4)));

__device__ inline unsigned short f2bf(float f){
  unsigned u = __float_as_uint(f);
  return (unsigned short)((u + 0x7fffu + ((u >> 16) & 1u)) >> 16);
}
__device__ inline float bf2f(unsigned short b){
  return __uint_as_float(((unsigned)b) << 16);
}

// ---------------- bf16 MFMA encoder GEMM, staged, split-K=4 (R6 geometry)
__global__ __launch_bounds__(256) void enc_mfma(
    const float* __restrict__ img, const float* __restrict__ txt,
    const unsigned short* __restrict__ Wt1, float* __restrict__ part)
{
  __shared__ unsigned short As[64 * 40];
  __shared__ unsigned short Bs[112 * 40];
  const int t = threadIdx.x;
  const int m0 = blockIdx.x * 64;
  const int s = blockIdx.y;
  const int l = t & 63, w = t >> 6;
  f32x4 acc[7];
  #pragma unroll
  for (int i = 0; i < 7; i++) acc[i] = f32x4{0.f, 0.f, 0.f, 0.f};

  for (int step = 0; step < ENC_STEPS; ++step) {
    const int kb = s * ENC_KSPLIT + step * 32;
    #pragma unroll
    for (int p = 0; p < 2; ++p) {
      const int c = t + p * 256;
      const int row = c >> 3, kq = c & 7;
      const int rowg = m0 + row;
      const int k = kb + kq * 4;
      float4 v = make_float4(0.f, 0.f, 0.f, 0.f);
      if (rowg < N_ENT) {
        if (k < 4096)      v = *(const float4*)(img + (size_t)rowg * 4096 + k);
        else if (k < 4396) v = *(const float4*)(txt + (size_t)rowg * 300 + (k - 4096));
      }
      ushort4 b;
      b.x = f2bf(v.x); b.y = f2bf(v.y); b.z = f2bf(v.z); b.w = f2bf(v.w);
      *(ushort4*)&As[row * 40 + kq * 4] = b;
    }
    {
      const int n = t >> 2, k16 = t & 3;
      *(uint4*)&Bs[n * 40 + k16 * 8] = *(const uint4*)(Wt1 + (size_t)n * KP_ENC + kb + k16 * 8);
      if (t < 192) {
        const int c = t + 256;
        const int n2 = c >> 2, k2 = c & 3;
        *(uint4*)&Bs[n2 * 40 + k2 * 8] = *(const uint4*)(Wt1 + (size_t)n2 * KP_ENC + kb + k2 * 8);
      }
    }
    __syncthreads();
    bf16x8 a = *(const bf16x8*)&As[(w * 16 + (l & 15)) * 40 + (l >> 4) * 8];
    #pragma unroll
    for (int ct = 0; ct < 7; ++ct) {
      bf16x8 bb = *(const bf16x8*)&Bs[(ct * 16 + (l & 15)) * 40 + (l >> 4) * 8];
      acc[ct] = __builtin_amdgcn_mfma_f32_16x16x32_bf16(a, bb, acc[ct], 0, 0, 0);
    }
    __syncthreads();
  }
  const int rb = m0 + w * 16 + (l >> 4) * 4;
  const int col = l & 15;
  float* pp = part + (size_t)s * MP_ENC * NP_ENC;
  #pragma unroll
  for (int ct = 0; ct < 7; ++ct)
    #pragma unroll
    for (int i = 0; i < 4; ++i)
      pp[(size_t)(rb + i) * NP_ENC + ct * 16 + col] = acc[ct][i];
}

// reduce split-K partials + bias -> feat1 rows [0,N_ENT) cols [0,100), bf16
__global__ __launch_bounds__(256) void enc_reduce(
    const float* __restrict__ part, const float* __restrict__ bias,
    unsigned short* __restrict__ feat1)
{
  int i = blockIdx.x * 256 + threadIdx.x;
  if (i >= N_ENT * 100) return;
  int r = i / 100, c = i % 100;
  float v = bias[c];
  #pragma unroll
  for (int s = 0; s < ENC_SPLIT; ++s) v += part[((size_t)s * MP_ENC + r) * NP_ENC + c];
  feat1[(size_t)r * 224 + c] = f2bf(v);
}

// ---------------- fused relation encoder: feat1[N_ENT+r][100+c] = bf16(relu(rel@W_ri + b_ri))
__global__ __launch_bounds__(256) void rel_enc(
    const float* __restrict__ rel, const float* __restrict__ W_ri,
    const float* __restrict__ b_ri, unsigned short* __restrict__ feat1)
{
  __shared__ float rs[300];
  const int r = blockIdx.x;
  const int t = threadIdx.x;
  if (t < 75) {
    float4 v = *(const float4*)(rel + (size_t)r * 300 + t * 4);
    *(float4*)&rs[t * 4] = v;
  }
  __syncthreads();
  if (t >= 100) return;
  float s = b_ri[t];
  for (int k = 0; k < 300; ++k) s = fmaf(rs[k], W_ri[(size_t)k * 100 + t], s);
  feat1[(size_t)(N_ENT + r) * 224 + 100 + t] = f2bf(fmaxf(s, 0.f));
}

// ---------------- egr1 = feat1[MROWS1,224] @ Wtg1^T -> bf16 [MROWS1,256]
__global__ __launch_bounds__(256) void egr1_mfma(
    const unsigned short* __restrict__ feat1, const unsigned short* __restrict__ Wtg1,
    unsigned short* __restrict__ egr1)
{
  __shared__ unsigned short As[64 * 40];
  __shared__ unsigned short Bs[256 * 40];
  const int t = threadIdx.x;
  const int m0 = blockIdx.x * 64;
  const int l = t & 63, w = t >> 6;
  f32x4 acc[16];
  #pragma unroll
  for (int i = 0; i < 16; i++) acc[i] = f32x4{0.f, 0.f, 0.f, 0.f};

  for (int step = 0; step < 7; ++step) {
    const int kb = step * 32;
    {
      const int row = t >> 2, kc = t & 3;
      *(uint4*)&As[row * 40 + kc * 8] = *(const uint4*)(feat1 + (size_t)(m0 + row) * 224 + kb + kc * 8);
    }
    #pragma unroll
    for (int p = 0; p < 4; ++p) {
      const int c = t + p * 256;
      const int n = c >> 2, k16 = c & 3;
      *(uint4*)&Bs[n * 40 + k16 * 8] = *(const uint4*)(Wtg1 + (size_t)n * 224 + kb + k16 * 8);
    }
    __syncthreads();
    bf16x8 a = *(const bf16x8*)&As[(w * 16 + (l & 15)) * 40 + (l >> 4) * 8];
    #pragma unroll
    for (int ct = 0; ct < 16; ++ct) {
      bf16x8 bb = *(const bf16x8*)&Bs[(ct * 16 + (l & 15)) * 40 + (l >> 4) * 8];
      acc[ct] = __builtin_amdgcn_mfma_f32_16x16x32_bf16(a, bb, acc[ct], 0, 0, 0);
    }
    __syncthreads();
  }
  const int rb = m0 + w * 16 + (l >> 4) * 4;
  const int col0 = l & 15;
  #pragma unroll
  for (int ct = 0; ct < 16; ++ct) {
    const int col = ct * 16 + col0;
    #pragma unroll
    for (int i = 0; i < 4; ++i)
      egr1[(size_t)(rb + i) * 256 + col] = f2bf(acc[ct][i]);
  }
}

// ---------------- hg2 = h1[NNODE,256](bf16) @ Wt2^T -> bf16 [NNODE,208]
__global__ __launch_bounds__(256) void gemm2_mfma(
    const unsigned short* __restrict__ h1, const unsigned short* __restrict__ Wt2,
    unsigned short* __restrict__ hg2)
{
  __shared__ unsigned short As[64 * 40];
  __shared__ unsigned short Bs[208 * 40];
  const int t = threadIdx.x;
  const int m0 = blockIdx.x * 64;
  const int l = t & 63, w = t >> 6;
  f32x4 acc[13];
  #pragma unroll
  for (int i = 0; i < 13; i++) acc[i] = f32x4{0.f, 0.f, 0.f, 0.f};

  for (int step = 0; step < 8; ++step) {
    const int kb = step * 32;
    {
      const int row = t >> 2, kc = t & 3;
      *(uint4*)&As[row * 40 + kc * 8] = *(const uint4*)(h1 + (size_t)(m0 + row) * 256 + kb + kc * 8);
    }
    #pragma unroll
    for (int p = 0; p < 4; ++p) {
      const int c = t + p * 256;
      if (c < 832) {
        const int n = c >> 2, k16 = c & 3;
        *(uint4*)&Bs[n * 40 + k16 * 8] = *(const uint4*)(Wt2 + (size_t)n * 256 + kb + k16 * 8);
      }
    }
    __syncthreads();
    bf16x8 a = *(const bf16x8*)&As[(w * 16 + (l & 15)) * 40 + (l >> 4) * 8];
    #pragma unroll
    for (int ct = 0; ct < 13; ++ct) {
      bf16x8 bb = *(const bf16x8*)&Bs[(ct * 16 + (l & 15)) * 40 + (l >> 4) * 8];
      acc[ct] = __builtin_amdgcn_mfma_f32_16x16x32_bf16(a, bb, acc[ct], 0, 0, 0);
    }
    __syncthreads();
  }
  const int rb = m0 + w * 16 + (l >> 4) * 4;
  const int col0 = l & 15;
  #pragma unroll
  for (int ct = 0; ct < 13; ++ct) {
    const int col = ct * 16 + col0;
    #pragma unroll
    for (int i = 0; i < 4; ++i)
      hg2[(size_t)(rb + i) * 208 + col] = f2bf(acc[ct][i]);
  }
}

// ---------------- out_new = embA[14976,416](bf16) @ Wteo^T + b_eo
__global__ __launch_bounds__(256) void fin_mfma(
    const unsigned short* __restrict__ embA, const unsigned short* __restrict__ Wteo,
    const float* __restrict__ b_eo, float* __restrict__ out)
{
  __shared__ unsigned short As[64 * 40];
  __shared__ unsigned short Bs[208 * 40];
  const int t = threadIdx.x;
  const int m0 = blockIdx.x * 64;
  const int l = t & 63, w = t >> 6;
  f32x4 acc[13];
  #pragma unroll
  for (int i = 0; i < 13; i++) acc[i] = f32x4{0.f, 0.f, 0.f, 0.f};

  for (int step = 0; step < 13; ++step) {
    const int kb = step * 32;
    {
      const int row = t >> 2, kc = t & 3;
      *(uint4*)&As[row * 40 + kc * 8] = *(const uint4*)(embA + (size_t)(m0 + row) * 416 + kb + kc * 8);
    }
    #pragma unroll
    for (int p = 0; p < 4; ++p) {
      const int c = t + p * 256;
      if (c < 832) {
        const int n = c >> 2, k16 = c & 3;
        *(uint4*)&Bs[n * 40 + k16 * 8] = *(const uint4*)(Wteo + (size_t)n * 416 + kb + k16 * 8);
      }
    }
    __syncthreads();
    bf16x8 a = *(const bf16x8*)&As[(w * 16 + (l & 15)) * 40 + (l >> 4) * 8];
    #pragma unroll
    for (int ct = 0; ct < 13; ++ct) {
      bf16x8 bb = *(const bf16x8*)&Bs[(ct * 16 + (l & 15)) * 40 + (l >> 4) * 8];
      acc[ct] = __builtin_amdgcn_mfma_f32_16x16x32_bf16(a, bb, acc[ct], 0, 0, 0);
    }
    __syncthreads();
  }
  const int rb = m0 + w * 16 + (l >> 4) * 4;
  const int col0 = l & 15;
  #pragma unroll
  for (int ct = 0; ct < 13; ++ct) {
    const int col = ct * 16 + col0;
    if (col < 200) {
      const float b = b_eo[col];
      #pragma unroll
      for (int i = 0; i < 4; ++i) {
        const int r = rb + i;
        if (r < N_ENT) out[(size_t)r * 200 + col] = acc[ct][i] + b;
      }
    }
  }
}

// ---------------- fused weight prep: Wt1(enc), Wtg1, Wt2, Wteo
__global__ __launch_bounds__(256) void wt_all_k(
    const float* __restrict__ W_it, const float* __restrict__ W_g1,
    const float* __restrict__ W_g2, const float* __restrict__ W_eo,
    unsigned short* __restrict__ Wt1, unsigned short* __restrict__ Wtg1,
    unsigned short* __restrict__ Wt2, unsigned short* __restrict__ Wteo)
{
  int i = blockIdx.x * 256 + threadIdx.x;
  if (i < NP_ENC * KP_ENC) {
    int n = i / KP_ENC, k = i % KP_ENC;
    float v = (n < 100 && k < 4396) ? W_it[(size_t)k * 100 + n] : 0.f;
    Wt1[i] = f2bf(v);
    return;
  }
  i -= NP_ENC * KP_ENC;
  if (i < 256 * 224) {
    int n = i / 224, k = i % 224;
    float v = (k < 200) ? W_g1[(size_t)k * 256 + n] : 0.f;
    Wtg1[i] = f2bf(v);
    return;
  }
  i -= 256 * 224;
  if (i < 208 * 256) {
    int n = i >> 8, k = i & 255;
    float v = (n < 200) ? W_g2[(size_t)k * 200 + n] : 0.f;
    Wt2[i] = f2bf(v);
    return;
  }
  i -= 208 * 256;
  if (i < 208 * 416) {
    int n = i / 416, k = i % 416;
    float v = (n < 200 && k < 400) ? W_eo[(size_t)k * 200 + n] : 0.f;
    Wteo[i] = f2bf(v);
  }
}

// ---------------- generic f32 GEMM (small: relation output encoder only)
template<bool RELU, bool HASBIAS>
__global__ __launch_bounds__(256) void gemm_f32(
    const float* __restrict__ A1, int K1, const float* __restrict__ A2,
    const float* __restrict__ B, const float* __restrict__ bias,
    float* __restrict__ C, int M, int K, int N)
{
  constexpr int BM = 64, BN = 128, BK = 16;
  __shared__ float As[BK][BM + 4];
  __shared__ float Bs[BK][BN];
  const int t = threadIdx.x;
  const int m0 = blockIdx.y * BM, n0 = blockIdx.x * BN;
  const int tr = t >> 4, tc = t & 15;
  const int tm0 = tr * 4, tn0 = tc * 8;
  const int K2 = K - K1;
  const int arow = t >> 2, aq = (t & 3) * 4;
  const int brow = t >> 4, bc0 = (t & 15) * 4;
  float acc[4][8];
  #pragma unroll
  for (int i = 0; i < 4; i++)
    #pragma unroll
    for (int j = 0; j < 8; j++) acc[i][j] = 0.f;

  for (int k0 = 0; k0 < K; k0 += BK) {
    {
      const int r = m0 + arow;
      const int k = k0 + aq;
      float4 v = make_float4(0.f, 0.f, 0.f, 0.f);
      if (r < M) {
        if (k + 3 < K1) {
          v = *(const float4*)(A1 + (size_t)r * K1 + k);
        } else if (k >= K1 && (k - K1) + 3 < K2) {
          v = *(const float4*)(A2 + (size_t)r * K2 + (k - K1));
        } else {
          float tmp[4] = {0.f, 0.f, 0.f, 0.f};
          #pragma unroll
          for (int j = 0; j < 4; j++) {
            int kj = k + j;
            if (kj < K) tmp[j] = (kj < K1) ? A1[(size_t)r * K1 + kj]
                                           : A2[(size_t)r * K2 + (kj - K1)];
          }
          v = make_float4(tmp[0], tmp[1], tmp[2], tmp[3]);
        }
      }
      As[aq + 0][arow] = v.x; As[aq + 1][arow] = v.y;
      As[aq + 2][arow] = v.z; As[aq + 3][arow] = v.w;
    }
    {
      const int k = k0 + brow;
      #pragma unroll
      for (int h = 0; h < 2; h++) {
        const int n = n0 + bc0 + h * 64;
        float4 v = make_float4(0.f, 0.f, 0.f, 0.f);
        if (k < K) {
          if (n + 3 < N) {
            v = *(const float4*)(B + (size_t)k * N + n);
          } else {
            float tmp[4] = {0.f, 0.f, 0.f, 0.f};
            for (int j = 0; j < 4; j++) if (n + j < N) tmp[j] = B[(size_t)k * N + n + j];
            v = make_float4(tmp[0], tmp[1], tmp[2], tmp[3]);
          }
        }
        *(float4*)&Bs[brow][bc0 + h * 64] = v;
      }
    }
    __syncthreads();
    #pragma unroll
    for (int k = 0; k < BK; k++) {
      float a[4], b[8];
      *(float4*)&a[0] = *(const float4*)&As[k][tm0];
      *(float4*)&b[0] = *(const float4*)&Bs[k][tn0];
      *(float4*)&b[4] = *(const float4*)&Bs[k][tn0 + 4];
      #pragma unroll
      for (int i = 0; i < 4; i++)
        #pragma unroll
        for (int j = 0; j < 8; j++) acc[i][j] = fmaf(a[i], b[j], acc[i][j]);
    }
    __syncthreads();
  }
  #pragma unroll
  for (int i = 0; i < 4; i++) {
    const int r = m0 + tm0 + i;
    if (r >= M) continue;
    #pragma unroll
    for (int j = 0; j < 8; j++) {
      const int c = n0 + tn0 + j;
      if (c >= N) continue;
      float v = acc[i][j];
      if (HASBIAS) v += bias[c];
      if (RELU) v = fmaxf(v, 0.f);
      C[(size_t)r * N + c] = v;
    }
  }
}

// ---------------- fused counting-sort infrastructure
__global__ __launch_bounds__(256) void hist2_k(
    const int* __restrict__ edst, const int* __restrict__ bx,
    int* __restrict__ ehist, int* __restrict__ nhist)
{
  int i = blockIdx.x * 256 + threadIdx.x;
  if (i < NEDGE) { atomicAdd(&ehist[edst[i]], 1); return; }
  i -= NEDGE;
  if (i < NNODE) atomicAdd(&nhist[bx[i]], 1);
}

__global__ __launch_bounds__(256) void scan1_k(
    const int* __restrict__ ehist, int* __restrict__ ebase, int* __restrict__ epart,
    const int* __restrict__ nhist, int* __restrict__ nbase, int* __restrict__ npart)
{
  __shared__ int s[256];
  const int t = threadIdx.x;
  const bool eregion = blockIdx.x < NB_E;
  const int b = eregion ? blockIdx.x : blockIdx.x - NB_E;
  const int n = eregion ? NNODE : N_ENT;
  const int* hist = eregion ? ehist : nhist;
  int* base = eregion ? ebase : nbase;
  int* partial = eregion ? epart : npart;
  const int i0 = b * 1024 + t * 4;
  int v[4];
  #pragma unroll
  for (int j = 0; j < 4; j++) v[j] = (i0 + j < n) ? hist[i0 + j] : 0;
  const int tsum = v[0] + v[1] + v[2] + v[3];
  s[t] = tsum;
  __syncthreads();
  #pragma unroll
  for (int off = 1; off < 256; off <<= 1) {
    int u = (t >= off) ? s[t - off] : 0;
    __syncthreads();
    s[t] += u;
    __syncthreads();
  }
  int run = s[t] - tsum;
  #pragma unroll
  for (int j = 0; j < 4; j++) {
    if (i0 + j < n) base[i0 + j] = run;
    run += v[j];
  }
  if (t == 255) partial[b] = s[255];
}

__global__ __launch_bounds__(256) void scan2_k(
    int* __restrict__ epart, int* __restrict__ ebase_end,
    int* __restrict__ npart, int* __restrict__ nbase_end)
{
  __shared__ int s[256];
  const int t = threadIdx.x;
  const bool eregion = blockIdx.x == 0;
  int* partial = eregion ? epart : npart;
  const int nb = eregion ? NB_E : NB_N;
  const int v = (t < nb) ? partial[t] : 0;
  s[t] = v;
  __syncthreads();
  #pragma unroll
  for (int off = 1; off < 256; off <<= 1) {
    int u = (t >= off) ? s[t - off] : 0;
    __syncthreads();
    s[t] += u;
    __syncthreads();
  }
  if (t < nb) partial[t] = s[t] - v;
  if (t == 255) *(eregion ? ebase_end : nbase_end) = s[255];
}

#define NB3_E 469  // ceil(NNODE/256)
__global__ __launch_bounds__(256) void scan3_k(
    int* __restrict__ ebase, const int* __restrict__ epart,
    int* __restrict__ nbase, const int* __restrict__ npart)
{
  if (blockIdx.x < NB3_E) {
    int i = blockIdx.x * 256 + threadIdx.x;
    if (i < NNODE) ebase[i] += epart[i >> 10];
  } else {
    int i = (blockIdx.x - NB3_E) * 256 + threadIdx.x;
    if (i < N_ENT) nbase[i] += npart[i >> 10];
  }
}

__global__ __launch_bounds__(256) void scatter2_k(
    const int* __restrict__ esrc, const int* __restrict__ edst, const float* __restrict__ ew,
    const int* __restrict__ bx, const int* __restrict__ bg,
    const int* __restrict__ ebase, int* __restrict__ ecur,
    float* __restrict__ s_w, int* __restrict__ s_src,
    int* __restrict__ s_en, int* __restrict__ s_gn,
    const int* __restrict__ nbase, int* __restrict__ ncur, int* __restrict__ node_of)
{
  int i = blockIdx.x * 256 + threadIdx.x;
  if (i < NEDGE) {
    int d = edst[i];
    int p = ebase[d] + atomicAdd(&ecur[d], 1);
    int s = esrc[i];
    s_w[p] = ew[i];
    s_src[p] = s;
    s_en[p] = bx[s];
    s_gn[p] = bg[s];
    return;
  }
  i -= NEDGE;
  if (i < NNODE) {
    int ent = bx[i];
    int p = nbase[ent] + atomicAdd(&ncur[ent], 1);
    node_of[p] = i;
  }
}

// ---------------- GCN layer 1 gather (bf16 table)
__global__ __launch_bounds__(256) void spmm1_g(
    const int* __restrict__ ebase, const float* __restrict__ s_w,
    const int* __restrict__ s_en, const int* __restrict__ s_gn,
    const unsigned short* __restrict__ egr1,
    const float* __restrict__ b_g1, unsigned short* __restrict__ h1)
{
  const int gid = blockIdx.x * blockDim.x + threadIdx.x;
  const int d = gid >> 6, lane = gid & 63;
  if (d >= NNODE) return;
  const int p0 = ebase[d], p1 = ebase[d + 1];
  float acc[4] = {0.f, 0.f, 0.f, 0.f};
  for (int p = p0; p < p1; ++p) {
    const float w = s_w[p];
    const int en = s_en[p], gn = s_gn[p];
    const ushort4 va = *(const ushort4*)(egr1 + (size_t)en * 256 + lane * 4);
    const ushort4 vb = *(const ushort4*)(egr1 + (size_t)(N_ENT + gn) * 256 + lane * 4);
    acc[0] += w * (bf2f(va.x) + bf2f(vb.x));
    acc[1] += w * (bf2f(va.y) + bf2f(vb.y));
    acc[2] += w * (bf2f(va.z) + bf2f(vb.z));
    acc[3] += w * (bf2f(va.w) + bf2f(vb.w));
  }
  const float4 b = ((const float4*)b_g1)[lane];
  ushort4 o;
  o.x = f2bf(fmaxf(acc[0] + b.x, 0.f));
  o.y = f2bf(fmaxf(acc[1] + b.y, 0.f));
  o.z = f2bf(fmaxf(acc[2] + b.z, 0.f));
  o.w = f2bf(fmaxf(acc[3] + b.w, 0.f));
  *(ushort4*)(h1 + (size_t)d * 256 + lane * 4) = o;
}

// ---------------- GCN layer 2 gather + bias + fused score; h2 bf16
__global__ __launch_bounds__(256) void spmm2_g(
    const int* __restrict__ ebase, const float* __restrict__ s_w,
    const int* __restrict__ s_src, const unsigned short* __restrict__ hg2,
    const float* __restrict__ b_g2, const float* __restrict__ W_e,
    unsigned short* __restrict__ h2, float* __restrict__ score)
{
  const int gid = blockIdx.x * blockDim.x + threadIdx.x;
  const int d = gid >> 6, lane = gid & 63;
  if (d >= NNODE) return;
  const int p0 = ebase[d], p1 = ebase[d + 1];
  float acc[4] = {0.f, 0.f, 0.f, 0.f};
  const int col = lane * 4;
  float sp = 0.f;
  if (lane < 50) {
    for (int p = p0; p < p1; ++p) {
      const float w = s_w[p];
      const ushort4 v = *(const ushort4*)(hg2 + (size_t)s_src[p] * 208 + col);
      acc[0] += w * bf2f(v.x); acc[1] += w * bf2f(v.y);
      acc[2] += w * bf2f(v.z); acc[3] += w * bf2f(v.w);
    }
    const float4 b = ((const float4*)b_g2)[lane];
    acc[0] += b.x; acc[1] += b.y; acc[2] += b.z; acc[3] += b.w;
    ushort4 o;
    o.x = f2bf(acc[0]); o.y = f2bf(acc[1]); o.z = f2bf(acc[2]); o.w = f2bf(acc[3]);
    *(ushort4*)(h2 + (size_t)d * 200 + col) = o;
    const float4 we = ((const float4*)W_e)[lane];
    sp = acc[0] * we.x + acc[1] * we.y + acc[2] * we.z + acc[3] * we.w;
  }
  #pragma unroll
  for (int off = 32; off; off >>= 1) sp += __shfl_xor(sp, off);
  if (lane == 0) score[d] = sp;
}

// ---------------- per-entity softmax + weighted sum + mean -> embA bf16 [14976][416]
__global__ __launch_bounds__(256) void ent_k(
    const int* __restrict__ nbase, const int* __restrict__ node_of,
    const unsigned short* __restrict__ h2, const float* __restrict__ score,
    unsigned short* __restrict__ embA)
{
  const int gid = blockIdx.x * blockDim.x + threadIdx.x;
  const int ent = gid >> 6, lane = gid & 63;
  if (ent >= N_ENT) return;
  const int p0 = nbase[ent], p1 = nbase[ent + 1];
  const int cnt = p1 - p0;
  float m, es;
  if (cnt <= 64) {
    // fast path: one score load per lane
    float sc = -3.4e38f;
    if (p0 + lane < p1) sc = score[node_of[p0 + lane]];
    m = sc;
    #pragma unroll
    for (int off = 32; off; off >>= 1) m = fmaxf(m, __shfl_xor(m, off));
    es = (p0 + lane < p1) ? __expf(sc - m) : 0.f;
    #pragma unroll
    for (int off = 32; off; off >>= 1) es += __shfl_xor(es, off);
  } else {
    m = -3.4e38f;
    for (int p = p0 + lane; p < p1; p += 64) m = fmaxf(m, score[node_of[p]]);
    #pragma unroll
    for (int off = 32; off; off >>= 1) m = fmaxf(m, __shfl_xor(m, off));
    es = 0.f;
    for (int p = p0 + lane; p < p1; p += 64) es += __expf(score[node_of[p]] - m);
    #pragma unroll
    for (int off = 32; off; off >>= 1) es += __shfl_xor(es, off);
  }
  const float inv_es = (cnt > 0) ? 1.f / es : 0.f;
  const float inv_cnt = 1.f / fmaxf((float)cnt, 1.f);
  float aw[4] = {0.f, 0.f, 0.f, 0.f};
  float am[4] = {0.f, 0.f, 0.f, 0.f};
  for (int p = p0; p < p1; ++p) {
    const int nd = node_of[p];
    const float z = __expf(score[nd] - m) * inv_es;
    if (lane < 50) {
      const ushort4 v = *(const ushort4*)(h2 + (size_t)nd * 200 + lane * 4);
      const float vx = bf2f(v.x), vy = bf2f(v.y), vz = bf2f(v.z), vw = bf2f(v.w);
      aw[0] += z * vx; aw[1] += z * vy; aw[2] += z * vz; aw[3] += z * vw;
      am[0] += vx; am[1] += vy; am[2] += vz; am[3] += vw;
    }
  }
  if (lane < 50) {
    ushort4 ow, om;
    ow.x = f2bf(aw[0]); ow.y = f2bf(aw[1]); ow.z = f2bf(aw[2]); ow.w = f2bf(aw[3]);
    om.x = f2bf(am[0] * inv_cnt); om.y = f2bf(am[1] * inv_cnt);
    om.z = f2bf(am[2] * inv_cnt); om.w = f2bf(am[3] * inv_cnt);
    *(ushort4*)(embA + (size_t)ent * 416 + lane * 4) = ow;
    *(ushort4*)(embA + (size_t)ent * 416 + 200 + lane * 4) = om;
  }
}

extern "C" void kernel_launch(void* const* d_in, const int* in_sizes, int n_in,
                              void* d_out, int out_size, void* d_ws, size_t ws_size,
                              hipStream_t stream)
{
  const float* img  = (const float*)d_in[0];
  const float* txt  = (const float*)d_in[1];
  const float* rel  = (const float*)d_in[2];
  const float* W_it = (const float*)d_in[3];
  const float* b_it = (const float*)d_in[4];
  const float* W_ri = (const float*)d_in[5];
  const float* b_ri = (const float*)d_in[6];
  const float* W_g1 = (const float*)d_in[7];
  const float* b_g1 = (const float*)d_in[8];
  const float* W_g2 = (const float*)d_in[9];
  const float* b_g2 = (const float*)d_in[10];
  const float* W_e  = (const float*)d_in[11];
  const float* W_eo = (const float*)d_in[13];
  const float* b_eo = (const float*)d_in[14];
  const float* W_r  = (const float*)d_in[15];
  const float* b_r  = (const float*)d_in[16];
  const float* ew   = (const float*)d_in[17];
  const int*   bx   = (const int*)d_in[18];
  const int*   bg   = (const int*)d_in[19];
  const int*   esrc = (const int*)d_in[20];
  const int*   edst = (const int*)d_in[21];

  float* ws = (float*)d_ws;
  size_t off = 0;
  auto alloc = [&](size_t n){ size_t r = off; off += (n + 255) & ~(size_t)255; return r; };
  unsigned short* feat1 = (unsigned short*)(ws + alloc((size_t)MROWS1 * 224 / 2));
  unsigned short* egr1  = (unsigned short*)(ws + alloc((size_t)MROWS1 * 256 / 2));
  unsigned short* h1    = (unsigned short*)(ws + alloc((size_t)NNODE * 256 / 2));
  unsigned short* hg2   = (unsigned short*)(ws + alloc((size_t)NNODE * 208 / 2));
  unsigned short* embA  = (unsigned short*)(ws + alloc((size_t)MP_ENC * 416 / 2));
  unsigned short* h2    = (unsigned short*)(ws + alloc((size_t)NNODE * 200 / 2));
  float* part  = ws + alloc((size_t)ENC_SPLIT * MP_ENC * NP_ENC);
  float* score = ws + alloc(NNODE);
  size_t cnt0 = alloc((size_t)NNODE * 2 + (size_t)N_ENT * 2);
  int* ehist = (int*)(ws + cnt0);
  int* ecur  = ehist + NNODE;
  int* nhist = ecur + NNODE;
  int* ncur  = nhist + N_ENT;
  int* ebase = (int*)(ws + alloc(NNODE + 1));
  int* nbase = (int*)(ws + alloc(N_ENT + 1));
  int* epart = (int*)(ws + alloc(256));
  int* npart = (int*)(ws + alloc(256));
  float* s_w  = ws + alloc(NEDGE);
  int* s_src  = (int*)(ws + alloc(NEDGE));
  int* s_en   = (int*)(ws + alloc(NEDGE));
  int* s_gn   = (int*)(ws + alloc(NEDGE));
  int* node_of = (int*)(ws + alloc(NNODE));
  unsigned short* Wt1  = (unsigned short*)(ws + alloc((size_t)NP_ENC * KP_ENC / 2));
  unsigned short* Wtg1 = (unsigned short*)(ws + alloc((size_t)256 * 224 / 2));
  unsigned short* Wt2  = (unsigned short*)(ws + alloc((size_t)208 * 256 / 2));
  unsigned short* Wteo = (unsigned short*)(ws + alloc((size_t)208 * 416 / 2));

  dim3 blk(256);

  // ---- memsets
  hipMemsetAsync(ehist, 0, ((size_t)NNODE * 2 + (size_t)N_ENT * 2) * 4, stream);
  hipMemsetAsync(feat1, 0, (size_t)MROWS1 * 224 * 2, stream);
  hipMemsetAsync(embA,  0, (size_t)MP_ENC * 416 * 2, stream);

  // ---- CSR build
  hist2_k<<<ceil_div(NEDGE + NNODE, 256), blk, 0, stream>>>(edst, bx, ehist, nhist);
  scan1_k<<<NB_E + NB_N, blk, 0, stream>>>(ehist, ebase, epart, nhist, nbase, npart);
  scan2_k<<<2, blk, 0, stream>>>(epart, ebase + NNODE, npart, nbase + N_ENT);
  scan3_k<<<NB3_E + ceil_div(N_ENT, 256), blk, 0, stream>>>(ebase, epart, nbase, npart);
  scatter2_k<<<ceil_div(NEDGE + NNODE, 256), blk, 0, stream>>>(
      esrc, edst, ew, bx, bg, ebase, ecur, s_w, s_src, s_en, s_gn, nbase, ncur, node_of);

  // ---- weight prep (fused)
  wt_all_k<<<ceil_div(NP_ENC * KP_ENC + 256 * 224 + 208 * 256 + 208 * 416, 256), blk, 0, stream>>>(
      W_it, W_g1, W_g2, W_eo, Wt1, Wtg1, Wt2, Wteo);

  // ---- encoders (entity MFMA split-K + reduce; relation fused into feat1)
  enc_mfma<<<dim3(MP_ENC / 64, ENC_SPLIT), blk, 0, stream>>>(img, txt, Wt1, part);
  enc_reduce<<<ceil_div(N_ENT * 100, 256), blk, 0, stream>>>(part, b_it, feat1);
  rel_enc<<<N_REL, blk, 0, stream>>>(rel, W_ri, b_ri, feat1);

  // ---- combined table + GCN layer 1 gather
  egr1_mfma<<<MROWS1 / 64, blk, 0, stream>>>(feat1, Wtg1, egr1);
  spmm1_g<<<ceil_div(NNODE * 64, 256), blk, 0, stream>>>(
      ebase, s_w, s_en, s_gn, egr1, b_g1, h1);

  // ---- GCN layer 2
  gemm2_mfma<<<NNODE / 64, blk, 0, stream>>>(h1, Wt2, hg2);
  spmm2_g<<<ceil_div(NNODE * 64, 256), blk, 0, stream>>>(
      ebase, s_w, s_src, hg2, b_g2, W_e, h2, score);

  // ---- per-entity softmax + weighted sum + mean -> embA (bf16)
  ent_k<<<ceil_div(N_ENT * 64, 256), blk, 0, stream>>>(nbase, node_of, h2, score, embA);

  // ---- final projections
  float* out_new = (float*)d_out;
  float* out_rel = out_new + (size_t)N_ENT * 200;
  fin_mfma<<<MP_ENC / 64, blk, 0, stream>>>(embA, Wteo, b_eo, out_new);
  gemm_f32<true, true><<<dim3(2, ceil_div(N_REL, 64)), blk, 0, stream>>>(
      rel, 300, rel, W_r, b_r, out_rel, N_REL, 300, 200);
}